// Round 5
// baseline (579.202 us; speedup 1.0000x reference)
//
#include <hip/hip_runtime.h>
#include <cmath>
#include <cstdint>

#define Bc   16
#define Cc   128
#define Nc   2000
#define Lc   128      // sequence length for mamba = C
#define DIc  4000
#define Sc   8
#define RKc  125      // DT_RANK
#define E2c  8000     // 2*DI
#define EXc  141      // DT_RANK + 2*S

// padded dims for the 8-phase W_in GEMM (xz = outn @ W_in^T)
#define KP1  2048     // 2000 -> mult of 128 (2 K-tiles of 64 per iter)
#define NP8  8192     // 8000 -> mult of 256
#define KT8  32       // K tiles of 64

__device__ __forceinline__ unsigned short f2bf(float f) {
  union { float f; unsigned int u; } v; v.f = f;
  unsigned int r = v.u + 0x7FFFu + ((v.u >> 16) & 1u);
  return (unsigned short)(r >> 16);
}

// ------------------------------------------------------------------
// K1: per-(b,c) instance-norm stats over N (mean, biased var)
// ------------------------------------------------------------------
__global__ void inorm_stats(const float* __restrict__ in,
                            float* __restrict__ mout,
                            float* __restrict__ vout) {
  int bc = blockIdx.x;
  const float* p = in + (long)bc * Nc;
  float s = 0.f, sq = 0.f;
  for (int i = threadIdx.x; i < Nc; i += blockDim.x) {
    float x = p[i]; s += x; sq += x * x;
  }
  #pragma unroll
  for (int o = 32; o > 0; o >>= 1) {
    s  += __shfl_down(s, o, 64);
    sq += __shfl_down(sq, o, 64);
  }
  __shared__ float ss[4], sqq[4];
  int w = threadIdx.x >> 6, lane = threadIdx.x & 63;
  if (lane == 0) { ss[w] = s; sqq[w] = sq; }
  __syncthreads();
  if (threadIdx.x == 0) {
    s  = ss[0] + ss[1] + ss[2] + ss[3];
    sq = sqq[0] + sqq[1] + sqq[2] + sqq[3];
    float mean = s / Nc;
    float var  = sq / Nc - mean * mean;
    mout[bc] = mean; vout[bc] = var;
  }
}

// ------------------------------------------------------------------
// K3: h^T = relu( inorm(x) * bnscale[c] * g[c] + b[c] ) transposed to
// (b, n, c) bf16 via LDS tile — the MFMA B^T operand layout.
// bn_scale folded in. grid (32, Bc), block 256.
// ------------------------------------------------------------------
__global__ void compute_h_t(const float* __restrict__ in,
                            const float* __restrict__ m,
                            const float* __restrict__ v,
                            const float* __restrict__ g,
                            const float* __restrict__ bb,
                            unsigned short* __restrict__ hT) {
  int b  = blockIdx.y;
  int n0 = blockIdx.x * 64;
  __shared__ unsigned short tile[64][132];
  __shared__ float bnsc_s[128];
  int t  = threadIdx.x;
  if (t < 128) {
    float s = 0.f;
    #pragma unroll
    for (int bb2 = 0; bb2 < Bc; bb2++) {
      float vv = v[bb2 * Cc + t];
      s += vv / (vv + 1e-3f);
    }
    bnsc_s[t] = rsqrtf(s / Bc + 1e-5f);
  }
  __syncthreads();
  int nl = t & 63, cb = t >> 6;
  int n  = n0 + nl;
  #pragma unroll 4
  for (int p = 0; p < 32; p++) {
    int c = p * 4 + cb;
    float val = 0.f;
    if (n < Nc) {
      int bc = b * Cc + c;
      float xn = (in[(long)bc * Nc + n] - m[bc]) * rsqrtf(v[bc] + 1e-3f);
      val = fmaxf(xn * bnsc_s[c] * g[c] + bb[c], 0.f);
    }
    tile[nl][c] = f2bf(val);
  }
  __syncthreads();
  int r = t >> 2, c0 = (t & 3) * 32;
  int nr = n0 + r;
  if (nr < Nc) {
    unsigned int* dst = (unsigned int*)(hT + ((long)b * 2048 + nr) * 128 + c0);
    const unsigned short* src = &tile[r][c0];
    #pragma unroll
    for (int j = 0; j < 16; j++)
      dst[j] = *(const unsigned int*)(src + 2 * j);
  }
}

// ------------------------------------------------------------------
// reduce ns slices (each `stride` apart) into dst; accum!=0 -> dst += sum
// ------------------------------------------------------------------
__global__ void reduce_slices(const float* __restrict__ sl, float* __restrict__ dst,
                              long stride, int ns, int total, int accum) {
  int i = blockIdx.x * 256 + threadIdx.x;
  if (i >= total) return;
  float s = accum ? dst[i] : 0.f;
  for (int k = 0; k < ns; k++) s += sl[(long)k * stride + i];
  dst[i] = s;
}

// ------------------------------------------------------------------
// reduce 4 xdbl slices (2048 x 256 each) -> xdbl f32 (2048 x 141)
// and xdbl_b bf16 (2048 x 128: cols 0..124, 125..127 zero)
// ------------------------------------------------------------------
__global__ void reduce_xdbl(const float* __restrict__ sl,
                            float* __restrict__ xd,
                            unsigned short* __restrict__ xdb) {
  int i = blockIdx.x * 256 + threadIdx.x;
  if (i >= 2048 * 144) return;
  int row = i / 144, c = i - row * 144;
  float s = 0.f;
  if (c < EXc) {
    #pragma unroll
    for (int k = 0; k < 4; k++) s += sl[(long)k * (2048 * 256) + (long)row * 256 + c];
    xd[(long)row * EXc + c] = s;
  }
  if (c < 128) xdb[(long)row * 128 + c] = f2bf(c < RKc ? s : 0.f);
}

// ------------------------------------------------------------------
// convert f32 (Rsrc x Csrc) to bf16 (R x Cdst) with zero padding
// ------------------------------------------------------------------
__global__ void cvt_pad_bf16(const float* __restrict__ src, unsigned short* __restrict__ dst,
                             int R, int Cdst, int Rsrc, int Csrc) {
  long i = (long)blockIdx.x * 256 + threadIdx.x;
  long total = (long)R * Cdst;
  if (i >= total) return;
  int r = (int)(i / Cdst), c = (int)(i - (long)r * Cdst);
  float v = (r < Rsrc && c < Csrc) ? src[(long)r * Csrc + c] : 0.f;
  dst[i] = f2bf(v);
}

// ------------------------------------------------------------------
// merged conv1_w + conv3_w bf16 conversion (both 128x128 pure cvt)
// ------------------------------------------------------------------
__global__ void cvt_convw2(const float* __restrict__ w1, const float* __restrict__ w3,
                           unsigned short* __restrict__ d1, unsigned short* __restrict__ d3) {
  int i = blockIdx.x * 256 + threadIdx.x;
  if (i < 16384) d1[i] = f2bf(w1[i]);
  else if (i < 32768) d3[i - 16384] = f2bf(w3[i - 16384]);
}

// ------------------------------------------------------------------
// merged W_x + W_dt bf16 conversions (padded)
// ------------------------------------------------------------------
__global__ void cvt_wx_wdt(const float* __restrict__ Wx, const float* __restrict__ Wdt,
                           unsigned short* __restrict__ bwx, unsigned short* __restrict__ bwdt) {
  int i = blockIdx.x * 256 + threadIdx.x;
  if (i < 256 * 4000) {
    int r = i / 4000, c = i - r * 4000;
    bwx[i] = f2bf(r < EXc ? Wx[(long)r * 4000 + c] : 0.f);
  } else {
    int j = i - 256 * 4000;
    if (j < 4096 * 128) {
      int r = j >> 7, c = j & 127;
      bwdt[j] = f2bf((r < DIc && c < RKc) ? Wdt[(long)r * RKc + c] : 0.f);
    }
  }
}

// ------------------------------------------------------------------
// K4: LayerNorm rows -> writes bf16, K-padded to KP1 with zeros
// ------------------------------------------------------------------
__global__ void ln_rows(const float* __restrict__ in,
                        const float* __restrict__ lw,
                        const float* __restrict__ lb,
                        unsigned short* __restrict__ An) {
  int row = blockIdx.x;
  const float* p = in + (long)row * Nc;
  float s = 0.f, sq = 0.f;
  for (int i = threadIdx.x; i < Nc; i += blockDim.x) {
    float x = p[i]; s += x; sq += x * x;
  }
  #pragma unroll
  for (int o = 32; o > 0; o >>= 1) {
    s  += __shfl_down(s, o, 64);
    sq += __shfl_down(sq, o, 64);
  }
  __shared__ float ss[4], sqq[4];
  __shared__ float smean, srstd;
  int w = threadIdx.x >> 6, lane = threadIdx.x & 63;
  if (lane == 0) { ss[w] = s; sqq[w] = sq; }
  __syncthreads();
  if (threadIdx.x == 0) {
    s  = ss[0] + ss[1] + ss[2] + ss[3];
    sq = sqq[0] + sqq[1] + sqq[2] + sqq[3];
    float mean = s / Nc;
    float var  = sq / Nc - mean * mean;
    smean = mean; srstd = rsqrtf(var + 1e-5f);
  }
  __syncthreads();
  float mu = smean, rs = srstd;
  for (int i = threadIdx.x; i < KP1; i += blockDim.x) {
    float v = 0.f;
    if (i < Nc) v = (p[i] - mu) * rs * lw[i] + lb[i];
    An[(long)row * KP1 + i] = f2bf(v);
  }
}

// ------------------------------------------------------------------
// bf16 MFMA GEMM, B^T layout: C[i][j] = sum_k A[i][k] * B[j][k]
// 128x128 tile, 4 waves (2x2). Deep-K loop (used for the xdbl GEMM).
// epi: 0 none; 1 softplus(v + ebias[gj]) via fast __logf/__expf;
//      2 silu(v) for j>=DIc; 3 v + ebias[gi] (+ addp[idx]) — conv epi.
// ------------------------------------------------------------------
typedef short v8s __attribute__((ext_vector_type(8)));
typedef float v4f __attribute__((ext_vector_type(4)));

typedef const __attribute__((address_space(1))) unsigned int* as1_cu32p;
typedef __attribute__((address_space(3))) unsigned int* as3_u32p;

__device__ __forceinline__ void gload_lds16(const unsigned short* g, unsigned short* l) {
  __builtin_amdgcn_global_load_lds((as1_cu32p)(uintptr_t)g,
                                   (as3_u32p)(uintptr_t)l, 16, 0, 0);
}

__device__ __forceinline__ float gemm_epilogue_val(float v, int epi, int gi, int gj,
                                                   const float* __restrict__ ebias,
                                                   const float* __restrict__ X, long idx) {
  if (epi == 1) {
    float tr = v + ebias[gj];
    float e = __expf(-fabsf(tr));
    v = fmaxf(tr, 0.f) + __logf(1.f + e);      // softplus, fast transcendentals
  } else if (epi == 2) {
    if (gj >= DIc) v = v / (1.f + __expf(-v)); // silu on z half
  } else if (epi == 3) {
    v += ebias[gi];
    if (X) v += X[idx];
  }
  return v;
}

__global__ __launch_bounds__(256, 4)
void gemm_mfma_bt(const unsigned short* __restrict__ A,
                  const unsigned short* __restrict__ B,
                  float* C, int NN, int K, int lda, int ldb, int ldc,
                  long sA, long sB, long sC,
                  int KS, int Klen, long sliceStride,
                  int epi, const float* __restrict__ ebias,
                  const float* __restrict__ addp) {
  __shared__ unsigned short As[128 * 32];
  __shared__ unsigned short Bs[128 * 32];

  int z = blockIdx.z;
  int batch = z / KS, ks = z - batch * KS;
  const unsigned short* Ab = A + (long)batch * sA;
  const unsigned short* Bb = B + (long)batch * sB;
  float* Cs = C + (long)batch * sC + (long)ks * sliceStride;
  const float* X = addp ? addp + (long)batch * sC : nullptr;

  int k0 = ks * Klen;
  int kend = min(K, k0 + Klen);

  int i0 = blockIdx.y * 128;
  int j0 = blockIdx.x * 128;

  int t = threadIdx.x;
  int wave = t >> 6, lane = t & 63;
  int wm = wave >> 1, wn = wave & 1;

  int srow = lane >> 2;     // 0..15
  int scol = lane & 3;      // k-chunk (8 bf16 = 16B)
  const unsigned short* gA0 = Ab + (long)(i0 + wave * 32 + srow) * lda + scol * 8;
  const unsigned short* gA1 = gA0 + (long)16 * lda;
  const unsigned short* gB0 = Bb + (long)(j0 + wave * 32 + srow) * ldb + scol * 8;
  const unsigned short* gB1 = gB0 + (long)16 * ldb;
  unsigned short* lA0 = As + (wave * 32) * 32;
  unsigned short* lA1 = As + (wave * 32 + 16) * 32;
  unsigned short* lB0 = Bs + (wave * 32) * 32;
  unsigned short* lB1 = Bs + (wave * 32 + 16) * 32;

  int fr = lane & 15;       // input-frag row index
  int kq = lane >> 4;       // k-quad (8 elements each)

  v4f acc[4][4] = {};

  for (int kt = k0; kt < kend; kt += 32) {
    gload_lds16(gA0 + kt, lA0);
    gload_lds16(gA1 + kt, lA1);
    gload_lds16(gB0 + kt, lB0);
    gload_lds16(gB1 + kt, lB1);
    __syncthreads();

    v8s af[4], bfr[4];
    #pragma unroll
    for (int mt = 0; mt < 4; mt++)
      af[mt] = *(const v8s*)&As[(wm * 64 + mt * 16 + fr) * 32 + kq * 8];
    #pragma unroll
    for (int nt = 0; nt < 4; nt++)
      bfr[nt] = *(const v8s*)&Bs[(wn * 64 + nt * 16 + fr) * 32 + kq * 8];

    #pragma unroll
    for (int mt = 0; mt < 4; mt++)
      #pragma unroll
      for (int nt = 0; nt < 4; nt++)
        acc[mt][nt] = __builtin_amdgcn_mfma_f32_16x16x32_bf16(
            af[mt], bfr[nt], acc[mt][nt], 0, 0, 0);
    __syncthreads();
  }

  // C/D layout: row=(lane>>4)*4+reg (A's m), col=lane&15 (B's n)
  int orow = (lane >> 4) * 4;
  int ocol = lane & 15;
  #pragma unroll
  for (int mt = 0; mt < 4; mt++) {
    #pragma unroll
    for (int nt = 0; nt < 4; nt++) {
      int gi = i0 + wm * 64 + mt * 16 + orow;
      int gj = j0 + wn * 64 + nt * 16 + ocol;
      if (gj >= NN) continue;
      #pragma unroll
      for (int r = 0; r < 4; r++) {
        long idx = (long)(gi + r) * ldc + gj;
        Cs[idx] = gemm_epilogue_val(acc[mt][nt][r], epi, gi + r, gj, ebias, X, idx);
      }
    }
  }
}

// ------------------------------------------------------------------
// Single-stage K=128 GEMM (conv1/conv3/dt). Same 128x128 tile and
// fragment layout as gemm_mfma_bt, but the ENTIRE K=128 strip of both
// operands is staged in one burst (16 global_load_lds per thread, all
// in flight), ONE barrier, then 64 MFMAs. Removes the 4x sequential
// HBM-latency exposure + 8 barriers that made K=128 runs of the deep-K
// loop latency-bound (measured MfmaUtil 0.7%).
// LDS layout [4 kchunk][128 row][32 k] keeps every global_load_lds
// destination wave-uniform-linear. lda = ldb = 128 (contiguous).
// 64 KiB LDS -> 2 blocks/CU.
// ------------------------------------------------------------------
__global__ __launch_bounds__(256, 2)
void gemm_k128(const unsigned short* __restrict__ A,
               const unsigned short* __restrict__ B,
               float* C, int NN, int ldc,
               long sA, long sB, long sC,
               int epi, const float* __restrict__ ebias,
               const float* __restrict__ addp) {
  __shared__ unsigned short As[4 * 128 * 32];   // 32 KiB
  __shared__ unsigned short Bs[4 * 128 * 32];   // 32 KiB

  int batch = blockIdx.z;
  const unsigned short* Ab = A + (long)batch * sA;
  const unsigned short* Bb = B + (long)batch * sB;
  float* Cs = C + (long)batch * sC;
  const float* X = addp ? addp + (long)batch * sC : nullptr;

  int i0 = blockIdx.y * 128;
  int j0 = blockIdx.x * 128;

  int t = threadIdx.x;
  int wave = t >> 6, lane = t & 63;
  int wm = wave >> 1, wn = wave & 1;
  int srow = lane >> 2, scol = lane & 3;

  const unsigned short* gA0 = Ab + (long)(i0 + wave * 32 + srow) * 128 + scol * 8;
  const unsigned short* gB0 = Bb + (long)(j0 + wave * 32 + srow) * 128 + scol * 8;

  // one burst: 16 loads/thread, all outstanding together
  #pragma unroll
  for (int kt = 0; kt < 4; kt++) {
    gload_lds16(gA0 + kt * 32,            As + kt * 4096 + (wave * 32) * 32);
    gload_lds16(gA0 + 16 * 128 + kt * 32, As + kt * 4096 + (wave * 32 + 16) * 32);
    gload_lds16(gB0 + kt * 32,            Bs + kt * 4096 + (wave * 32) * 32);
    gload_lds16(gB0 + 16 * 128 + kt * 32, Bs + kt * 4096 + (wave * 32 + 16) * 32);
  }
  __syncthreads();   // compiler emits vmcnt(0) drain before barrier

  int fr = lane & 15, kq = lane >> 4;
  v4f acc[4][4] = {};
  #pragma unroll
  for (int kk = 0; kk < 4; kk++) {
    v8s af[4], bfr[4];
    #pragma unroll
    for (int mt = 0; mt < 4; mt++)
      af[mt] = *(const v8s*)&As[kk * 4096 + (wm * 64 + mt * 16 + fr) * 32 + kq * 8];
    #pragma unroll
    for (int nt = 0; nt < 4; nt++)
      bfr[nt] = *(const v8s*)&Bs[kk * 4096 + (wn * 64 + nt * 16 + fr) * 32 + kq * 8];
    #pragma unroll
    for (int mt = 0; mt < 4; mt++)
      #pragma unroll
      for (int nt = 0; nt < 4; nt++)
        acc[mt][nt] = __builtin_amdgcn_mfma_f32_16x16x32_bf16(
            af[mt], bfr[nt], acc[mt][nt], 0, 0, 0);
  }

  int orow = (lane >> 4) * 4;
  int ocol = lane & 15;
  #pragma unroll
  for (int mt = 0; mt < 4; mt++) {
    #pragma unroll
    for (int nt = 0; nt < 4; nt++) {
      int gi = i0 + wm * 64 + mt * 16 + orow;
      int gj = j0 + wn * 64 + nt * 16 + ocol;
      if (gj >= NN) continue;
      #pragma unroll
      for (int r = 0; r < 4; r++) {
        long idx = (long)(gi + r) * ldc + gj;
        Cs[idx] = gemm_epilogue_val(acc[mt][nt][r], epi, gi + r, gj, ebias, X, idx);
      }
    }
  }
}

// ==================================================================
// Shared macros for the 8-phase 256x256 kernels (file scope; undef'd
// after the last user). MM references local aF/bF/acc of each kernel.
// ==================================================================
#define MM(mh, nh) do {                                                       \
    _Pragma("unroll")                                                         \
    for (int mt_ = 0; mt_ < 4; mt_++) {                                       \
      _Pragma("unroll")                                                       \
      for (int nt_ = 0; nt_ < 2; nt_++) {                                     \
        acc[(mh) * 4 + mt_][(nh) * 2 + nt_] = __builtin_amdgcn_mfma_f32_16x16x32_bf16( \
            aF[mt_][0], bF[nh][nt_][0], acc[(mh) * 4 + mt_][(nh) * 2 + nt_], 0, 0, 0); \
        acc[(mh) * 4 + mt_][(nh) * 2 + nt_] = __builtin_amdgcn_mfma_f32_16x16x32_bf16( \
            aF[mt_][1], bF[nh][nt_][1], acc[(mh) * 4 + mt_][(nh) * 2 + nt_], 0, 0, 0); \
      } }                                                                     \
  } while (0)
#define FENCE()   __asm__ volatile("" ::: "memory")
#define BARRIER() do { FENCE(); __builtin_amdgcn_s_barrier(); FENCE(); } while (0)
#define WAIT_LGKM0() do { __asm__ volatile("s_waitcnt lgkmcnt(0)" ::: "memory"); \
                          __builtin_amdgcn_sched_barrier(0); } while (0)
#define WAIT_VM(n) __asm__ volatile("s_waitcnt vmcnt(" #n ")" ::: "memory")

// ------------------------------------------------------------------
// W_in GEMM, 8-phase 256x256 schedule (T2 swizzle + T3/T4 counted vmcnt
// + T5 setprio). C[i][j] = sum_k An[i][k] * Bwin[j][k], epi: silu on
// j >= DIc. M=2048, N=8192 (stores guarded at 8000), K=2048.
// ------------------------------------------------------------------
__global__ __launch_bounds__(512, 2)
void gemm_win_8ph(const unsigned short* __restrict__ A,   // 2048 x 2048 bf16
                  const unsigned short* __restrict__ B,   // 8192 x 2048 bf16
                  float* __restrict__ C) {                // 2048 x 8000 f32
  __shared__ unsigned short As8[2 * 2 * 128 * 64];        // 64 KiB
  __shared__ unsigned short Bs8[2 * 2 * 128 * 64];        // 64 KiB

  const int lda = KP1, ldb = KP1, ldc = E2c;

  int i0 = blockIdx.y * 256;
  int j0 = blockIdx.x * 256;

  int t = threadIdx.x;
  int w = t >> 6, l = t & 63;
  int wm = w >> 2;          // 0..1
  int wn = w & 3;           // 0..3
  int w8 = w << 3;

  // staging per-thread constants (pre-swizzled global column chunk)
  int rw     = w8 + (l >> 3);                  // 0..63
  int scol16 = (l & 7) ^ ((l >> 3) & 7);
  const unsigned short* pA = A + (long)(i0 + rw) * lda + scol16 * 8;
  int gjrow = ((rw >> 5) << 6) + (rw & 31);
  const unsigned short* pB = B + (long)(j0 + gjrow) * ldb + scol16 * 8;

  // compute-side per-lane constants
  int fr   = l & 15;
  int kq   = l >> 4;
  int inr0 = ((kq ^ (fr & 7)) << 4);           // swizzled byte-in-row, ks=0
  int inr1 = inr0 ^ 64;                        // ks=1

  const char* asb = (const char*)As8;
  const char* bsb = (const char*)Bs8;

  v4f acc[8][4] = {};
  v8s aF[4][2], bF[2][2][2];

#define ST_A(bufi, h, tile) do {                                              \
    int kt_ = ((tile) < KT8 ? (tile) : (KT8 - 1)) * 64;                       \
    gload_lds16(pA + (long)((h) * 64) * lda + kt_,                            \
                As8 + (size_t)((((bufi) * 2 + (h)) * 128 + w8) * 64));        \
    gload_lds16(pA + (long)(128 + (h) * 64) * lda + kt_,                      \
                As8 + (size_t)((((bufi) * 2 + (h)) * 128 + 64 + w8) * 64));   \
  } while (0)
#define ST_B(bufi, h, tile) do {                                              \
    int kt_ = ((tile) < KT8 ? (tile) : (KT8 - 1)) * 64;                       \
    gload_lds16(pB + (long)((h) * 32) * ldb + kt_,                            \
                Bs8 + (size_t)((((bufi) * 2 + (h)) * 128 + w8) * 64));        \
    gload_lds16(pB + (long)(128 + (h) * 32) * ldb + kt_,                      \
                Bs8 + (size_t)((((bufi) * 2 + (h)) * 128 + 64 + w8) * 64));   \
  } while (0)
#define LD_A(bufi, mh) do {                                                   \
    const char* ab_ = asb + (size_t)(((((bufi) * 2 + (mh)) * 128) + wm * 64 + fr) * 128); \
    aF[0][0] = *(const v8s*)(ab_ +    0 + inr0); aF[0][1] = *(const v8s*)(ab_ +    0 + inr1); \
    aF[1][0] = *(const v8s*)(ab_ + 2048 + inr0); aF[1][1] = *(const v8s*)(ab_ + 2048 + inr1); \
    aF[2][0] = *(const v8s*)(ab_ + 4096 + inr0); aF[2][1] = *(const v8s*)(ab_ + 4096 + inr1); \
    aF[3][0] = *(const v8s*)(ab_ + 6144 + inr0); aF[3][1] = *(const v8s*)(ab_ + 6144 + inr1); \
  } while (0)
#define LD_B(bufi, nh) do {                                                   \
    const char* bb_ = bsb + (size_t)(((((bufi) * 2 + (nh)) * 128) + wn * 32 + fr) * 128); \
    bF[nh][0][0] = *(const v8s*)(bb_ +    0 + inr0); bF[nh][0][1] = *(const v8s*)(bb_ +    0 + inr1); \
    bF[nh][1][0] = *(const v8s*)(bb_ + 2048 + inr0); bF[nh][1][1] = *(const v8s*)(bb_ + 2048 + inr1); \
  } while (0)

  // prologue: tile0 fully -> buf0; tile1 {Ah0,Bh1,Ah1} -> buf1 (6 in flight)
  ST_A(0, 0, 0); ST_B(0, 0, 0); ST_B(0, 1, 0); ST_A(0, 1, 0);
  ST_A(1, 0, 1); ST_B(1, 1, 1); ST_A(1, 1, 1);
  WAIT_VM(6);
  BARRIER();

  #pragma unroll 1
  for (int it = 0; it < KT8 / 2; ++it) {
    int u = 2 * it;
    // ---- p1: (mh0,nh0) from buf0 ----
    LD_A(0, 0); LD_B(0, 0); ST_B(1, 0, u + 1);
    BARRIER(); WAIT_LGKM0();
    __builtin_amdgcn_s_setprio(1); MM(0, 0); __builtin_amdgcn_s_setprio(0);
    BARRIER();
    // ---- p2: (mh0,nh1) ----
    LD_B(0, 1); ST_A(0, 0, u + 2);
    BARRIER(); WAIT_LGKM0();
    __builtin_amdgcn_s_setprio(1); MM(0, 1); __builtin_amdgcn_s_setprio(0);
    BARRIER();
    // ---- p3: (mh1,nh1) ----
    LD_A(0, 1); ST_B(0, 1, u + 2);
    BARRIER(); WAIT_LGKM0();
    __builtin_amdgcn_s_setprio(1); MM(1, 1); __builtin_amdgcn_s_setprio(0);
    BARRIER();
    // ---- p4: (mh1,nh0), vmcnt(6): tile u+1 fully landed ----
    ST_A(0, 1, u + 2);
    BARRIER();
    __builtin_amdgcn_s_setprio(1); MM(1, 0); __builtin_amdgcn_s_setprio(0);
    WAIT_VM(6);
    BARRIER();
    // ---- p5: (mh0,nh0) from buf1 ----
    LD_A(1, 0); LD_B(1, 0); ST_B(0, 0, u + 2);
    BARRIER(); WAIT_LGKM0();
    __builtin_amdgcn_s_setprio(1); MM(0, 0); __builtin_amdgcn_s_setprio(0);
    BARRIER();
    // ---- p6: (mh0,nh1) ----
    LD_B(1, 1); ST_A(1, 0, u + 3);
    BARRIER(); WAIT_LGKM0();
    __builtin_amdgcn_s_setprio(1); MM(0, 1); __builtin_amdgcn_s_setprio(0);
    BARRIER();
    // ---- p7: (mh1,nh1) ----
    LD_A(1, 1); ST_B(1, 1, u + 3);
    BARRIER(); WAIT_LGKM0();
    __builtin_amdgcn_s_setprio(1); MM(1, 1); __builtin_amdgcn_s_setprio(0);
    BARRIER();
    // ---- p8: (mh1,nh0), vmcnt(6): tile u+2 fully landed ----
    ST_A(1, 1, u + 3);
    BARRIER();
    __builtin_amdgcn_s_setprio(1); MM(1, 0); __builtin_amdgcn_s_setprio(0);
    WAIT_VM(6);
    BARRIER();
  }
  WAIT_VM(0);   // drain clamped tail prefetches before endpgm

  // epilogue: row=(lane>>4)*4+reg, col=lane&15
  int orow4 = (l >> 4) * 4;
  int ocol  = l & 15;
  #pragma unroll
  for (int m = 0; m < 8; m++) {
    int gi = i0 + wm * 128 + m * 16 + orow4;
    #pragma unroll
    for (int n = 0; n < 4; n++) {
      int gj = j0 + wn * 64 + n * 16 + ocol;
      if (gj >= E2c) continue;
      #pragma unroll
      for (int r = 0; r < 4; r++) {
        float v = acc[m][n][r];
        if (gj >= DIc) v = v / (1.f + __expf(-v));  // silu on z half
        C[(long)(gi + r) * ldc + gj] = v;
      }
    }
  }
#undef ST_A
#undef ST_B
#undef LD_A
#undef LD_B
}

// ------------------------------------------------------------------
// W_out GEMM, same 8-phase 256x256 schedule, split-K=4.
// C_slice[ks][i][j] = sum_{k in slice} yb[i][k] * Bwout[j][k]
// M=2048, N=2048 (stores guarded at Nc=2000), K=4000 padded to 4096
// logical. Tail tiles redirect the global_load_lds source to a
// guaranteed-zero region (zsrc = Bwdt pad rows). lda=ldb=4000.
// ------------------------------------------------------------------
__global__ __launch_bounds__(512, 2)
void gemm_wout_8ph(const unsigned short* __restrict__ A,   // yb 2048 x 4000 bf16
                   const unsigned short* __restrict__ B,   // Bwout 2048 x 4000 bf16
                   float* __restrict__ C,                  // slices: 4 x 2048 x 2000 f32
                   const unsigned short* __restrict__ zsrc) {
  __shared__ unsigned short As8[2 * 2 * 128 * 64];
  __shared__ unsigned short Bs8[2 * 2 * 128 * 64];

  const int lda = 4000, ldb = 4000;

  int i0 = blockIdx.y * 256;
  int j0 = blockIdx.x * 256;
  int ks = blockIdx.z;
  int k0t = ks * 16;                           // first global K-tile of slice

  int t = threadIdx.x;
  int w = t >> 6, l = t & 63;
  int wm = w >> 2;
  int wn = w & 3;
  int w8 = w << 3;

  int rw     = w8 + (l >> 3);
  int scol16 = (l & 7) ^ ((l >> 3) & 7);
  const unsigned short* pA = A + (long)(i0 + rw) * lda + scol16 * 8;
  int gjrow = ((rw >> 5) << 6) + (rw & 31);
  const unsigned short* pB = B + (long)(j0 + gjrow) * ldb + scol16 * 8;

  int fr   = l & 15;
  int kq   = l >> 4;
  int inr0 = ((kq ^ (fr & 7)) << 4);
  int inr1 = inr0 ^ 64;

  const char* asb = (const char*)As8;
  const char* bsb = (const char*)Bs8;

  v4f acc[8][4] = {};
  v8s aF[4][2], bF[2][2][2];

#define ST_A2(bufi, h, lt) do {                                               \
    int gk_ = k0t + (((lt) < 16) ? (lt) : 15);                                \
    bool pad_ = (gk_ >= 62) && (gk_ == 63 || scol16 >= 4);                    \
    const unsigned short* s0_ = pad_ ? zsrc : pA + (long)((h) * 64) * lda + gk_ * 64;   \
    const unsigned short* s1_ = pad_ ? zsrc : pA + (long)(128 + (h) * 64) * lda + gk_ * 64; \
    gload_lds16(s0_, As8 + (size_t)((((bufi) * 2 + (h)) * 128 + w8) * 64));   \
    gload_lds16(s1_, As8 + (size_t)((((bufi) * 2 + (h)) * 128 + 64 + w8) * 64)); \
  } while (0)
#define ST_B2(bufi, h, lt) do {                                               \
    int gk_ = k0t + (((lt) < 16) ? (lt) : 15);                                \
    bool pad_ = (gk_ >= 62) && (gk_ == 63 || scol16 >= 4);                    \
    const unsigned short* s0_ = pad_ ? zsrc : pB + (long)((h) * 32) * ldb + gk_ * 64;   \
    const unsigned short* s1_ = pad_ ? zsrc : pB + (long)(128 + (h) * 32) * ldb + gk_ * 64; \
    gload_lds16(s0_, Bs8 + (size_t)((((bufi) * 2 + (h)) * 128 + w8) * 64));   \
    gload_lds16(s1_, Bs8 + (size_t)((((bufi) * 2 + (h)) * 128 + 64 + w8) * 64)); \
  } while (0)
#define LD_A2(bufi, mh) do {                                                  \
    const char* ab_ = asb + (size_t)(((((bufi) * 2 + (mh)) * 128) + wm * 64 + fr) * 128); \
    aF[0][0] = *(const v8s*)(ab_ +    0 + inr0); aF[0][1] = *(const v8s*)(ab_ +    0 + inr1); \
    aF[1][0] = *(const v8s*)(ab_ + 2048 + inr0); aF[1][1] = *(const v8s*)(ab_ + 2048 + inr1); \
    aF[2][0] = *(const v8s*)(ab_ + 4096 + inr0); aF[2][1] = *(const v8s*)(ab_ + 4096 + inr1); \
    aF[3][0] = *(const v8s*)(ab_ + 6144 + inr0); aF[3][1] = *(const v8s*)(ab_ + 6144 + inr1); \
  } while (0)
#define LD_B2(bufi, nh) do {                                                  \
    const char* bb_ = bsb + (size_t)(((((bufi) * 2 + (nh)) * 128) + wn * 32 + fr) * 128); \
    bF[nh][0][0] = *(const v8s*)(bb_ +    0 + inr0); bF[nh][0][1] = *(const v8s*)(bb_ +    0 + inr1); \
    bF[nh][1][0] = *(const v8s*)(bb_ + 2048 + inr0); bF[nh][1][1] = *(const v8s*)(bb_ + 2048 + inr1); \
  } while (0)

  // prologue: slice tile0 -> buf0; tile1 {Ah0,Bh1,Ah1} -> buf1
  ST_A2(0, 0, 0); ST_B2(0, 0, 0); ST_B2(0, 1, 0); ST_A2(0, 1, 0);
  ST_A2(1, 0, 1); ST_B2(1, 1, 1); ST_A2(1, 1, 1);
  WAIT_VM(6);
  BARRIER();

  #pragma unroll 1
  for (int it = 0; it < 8; ++it) {
    int u = 2 * it;
    LD_A2(0, 0); LD_B2(0, 0); ST_B2(1, 0, u + 1);
    BARRIER(); WAIT_LGKM0();
    __builtin_amdgcn_s_setprio(1); MM(0, 0); __builtin_amdgcn_s_setprio(0);
    BARRIER();
    LD_B2(0, 1); ST_A2(0, 0, u + 2);
    BARRIER(); WAIT_LGKM0();
    __builtin_amdgcn_s_setprio(1); MM(0, 1); __builtin_amdgcn_s_setprio(0);
    BARRIER();
    LD_A2(0, 1); ST_B2(0, 1, u + 2);
    BARRIER(); WAIT_LGKM0();
    __builtin_amdgcn_s_setprio(1); MM(1, 1); __builtin_amdgcn_s_setprio(0);
    BARRIER();
    ST_A2(0, 1, u + 2);
    BARRIER();
    __builtin_amdgcn_s_setprio(1); MM(1, 0); __builtin_amdgcn_s_setprio(0);
    WAIT_VM(6);
    BARRIER();
    LD_A2(1, 0); LD_B2(1, 0); ST_B2(0, 0, u + 2);
    BARRIER(); WAIT_LGKM0();
    __builtin_amdgcn_s_setprio(1); MM(0, 0); __builtin_amdgcn_s_setprio(0);
    BARRIER();
    LD_B2(1, 1); ST_A2(1, 0, u + 3);
    BARRIER(); WAIT_LGKM0();
    __builtin_amdgcn_s_setprio(1); MM(0, 1); __builtin_amdgcn_s_setprio(0);
    BARRIER();
    LD_A2(1, 1); ST_B2(1, 1, u + 3);
    BARRIER(); WAIT_LGKM0();
    __builtin_amdgcn_s_setprio(1); MM(1, 1); __builtin_amdgcn_s_setprio(0);
    BARRIER();
    ST_A2(1, 1, u + 3);
    BARRIER();
    __builtin_amdgcn_s_setprio(1); MM(1, 0); __builtin_amdgcn_s_setprio(0);
    WAIT_VM(6);
    BARRIER();
  }
  WAIT_VM(0);

  float* Cs = C + (long)ks * ((long)2048 * Nc);
  int orow4 = (l >> 4) * 4;
  int ocol  = l & 15;
  #pragma unroll
  for (int m = 0; m < 8; m++) {
    int gi = i0 + wm * 128 + m * 16 + orow4;
    #pragma unroll
    for (int n = 0; n < 4; n++) {
      int gj = j0 + wn * 64 + n * 16 + ocol;
      if (gj >= Nc) continue;
      #pragma unroll
      for (int r = 0; r < 4; r++)
        Cs[(long)(gi + r) * Nc + gj] = acc[m][n][r];
    }
  }
#undef ST_A2
#undef ST_B2
#undef LD_A2
#undef LD_B2
}

#undef MM
#undef FENCE
#undef BARRIER
#undef WAIT_LGKM0
#undef WAIT_VM

// ------------------------------------------------------------------
// K6: depthwise causal conv (DCONV=4) + silu; writes f32 xc and bf16 xcb
// ------------------------------------------------------------------
__global__ void dwconv_silu(const float* __restrict__ xz,
                            const float4* __restrict__ cw,
                            const float* __restrict__ cb,
                            float* __restrict__ xc,
                            unsigned short* __restrict__ xcb, int total) {
  int i = blockIdx.x * 256 + threadIdx.x;
  if (i >= total) return;
  int d  = i % DIc;
  int bl = i / DIc;
  int l  = bl % Lc;
  int b  = bl / Lc;
  float4 w = cw[d];
  float acc = cb[d];
  long rowbase = (long)(b * Lc) * E2c + d;
  int l0 = l - 3;
  if (l0     >= 0) acc += xz[rowbase + (long)l0       * E2c] * w.x;
  if (l0 + 1 >= 0) acc += xz[rowbase + (long)(l0 + 1) * E2c] * w.y;
  if (l0 + 2 >= 0) acc += xz[rowbase + (long)(l0 + 2) * E2c] * w.z;
  acc += xz[rowbase + (long)l * E2c] * w.w;
  float sv = acc / (1.f + __expf(-acc));
  xc[i] = sv;
  xcb[i] = f2bf(sv);
}

// ------------------------------------------------------------------
// K9: selective scan, 1 thread per (b,d), software-pipelined.
// dtv pre-softplus'd (dt-GEMM epilogue); z pre-silu'd (W_in epilogue).
// ------------------------------------------------------------------
#define SCU 4
__global__ __launch_bounds__(256)
void scan_kernel(const float* __restrict__ dtv,
                 const float* __restrict__ xdbl,
                 const float* __restrict__ xc,
                 const float* __restrict__ xzf,
                 const float* __restrict__ A_log,
                 const float* __restrict__ D_p,
                 unsigned short* __restrict__ yb) {
  int d = blockIdx.x * 256 + threadIdx.x;
  int b = blockIdx.y;
  if (d >= DIc) return;
  float Av[Sc];
  #pragma unroll
  for (int s = 0; s < Sc; s++) Av[s] = -__expf(A_log[d * Sc + s]);
  float Dp = D_p[d];
  float h[Sc];
  #pragma unroll
  for (int s = 0; s < Sc; s++) h[s] = 0.f;

  long base  = (long)(b * Lc) * DIc + d;
  long zbase = (long)(b * Lc) * E2c + DIc + d;
  const float* xrow = xdbl + (long)(b * Lc) * EXc + RKc;

  float d0[SCU], u0[SCU], z0[SCU], B0[SCU][Sc], C0[SCU][Sc];
  float d1[SCU], u1[SCU], z1[SCU], B1[SCU][Sc], C1[SCU][Sc];

#define LOADG(g, dd, uu, zz, BB, CC)                                        \
  { int l0_ = (g) * SCU;                                                    \
    _Pragma("unroll")                                                       \
    for (int u = 0; u < SCU; u++) {                                         \
      long idx = base + (long)(l0_ + u) * DIc;                              \
      dd[u] = dtv[idx];                                                     \
      uu[u] = xc[idx];                                                      \
      zz[u] = xzf[zbase + (long)(l0_ + u) * E2c];                           \
      const float* xr = xrow + (long)(l0_ + u) * EXc;                       \
      _Pragma("unroll")                                                     \
      for (int s = 0; s < Sc; s++) { BB[u][s] = xr[s]; CC[u][s] = xr[Sc + s]; } \
    } }

#define COMPG(g, dd, uu, zz, BB, CC)                                        \
  { int l0_ = (g) * SCU;                                                    \
    _Pragma("unroll")                                                       \
    for (int u = 0; u < SCU; u++) {                                         \
      float dv = dd[u], uv = uu[u];                                         \
      float du = dv * uv;                                                   \
      float p = 0.f;                                                        \
      _Pragma("unroll")                                                     \
      for (int s = 0; s < Sc; s++) {                                        \
        float dA = __expf(dv * Av[s]);                                      \
        h[s] = dA * h[s] + du * BB[u][s];                                   \
        p += h[s] * CC[u][s];                                               \
      }                                                                     \
      yb[base + (long)(l0_ + u) * DIc] = f2bf((p + uv * Dp) * zz[u]);       \
    } }

  LOADG(0, d0, u0, z0, B0, C0);
  #pragma unroll 1
  for (int g = 0; g < Lc / SCU; g += 2) {
    LOADG(g + 1, d1, u1, z1, B1, C1);
    COMPG(g, d0, u0, z0, B0, C0);
    if (g + 2 < Lc / SCU) LOADG(g + 2, d0, u0, z0, B0, C0);
    COMPG(g + 1, d1, u1, z1, B1, C1);
  }
#undef LOADG
#undef COMPG
}

// ------------------------------------------------------------------
// launch
// ------------------------------------------------------------------
extern "C" void kernel_launch(void* const* d_in, const int* in_sizes, int n_in,
                              void* d_out, int out_size, void* d_ws, size_t ws_size,
                              hipStream_t stream) {
  const float* x       = (const float*)d_in[0];
  const float* bn1_g   = (const float*)d_in[1];
  const float* bn1_b   = (const float*)d_in[2];
  const float* conv1_w = (const float*)d_in[3];
  const float* conv1_b = (const float*)d_in[4];
  const float* ln_w    = (const float*)d_in[5];
  const float* ln_b    = (const float*)d_in[6];
  const float* W_in    = (const float*)d_in[7];
  const float* convm_w = (const float*)d_in[8];
  const float* convm_b = (const float*)d_in[9];
  const float* W_x     = (const float*)d_in[10];
  const float* W_dt    = (const float*)d_in[11];
  const float* b_dt    = (const float*)d_in[12];
  const float* A_log   = (const float*)d_in[13];
  const float* D_p     = (const float*)d_in[14];
  const float* W_out   = (const float*)d_in[15];
  const float* bn3_g   = (const float*)d_in[16];
  const float* bn3_b   = (const float*)d_in[17];
  const float* conv3_w = (const float*)d_in[18];
  const float* conv3_b = (const float*)d_in[19];
  float* out = (float*)d_out;
  float* ws  = (float*)d_ws;

  const int TOT  = Bc * Cc * Nc;     // 4,096,000
  const int ROWS = Bc * Lc;          // 2048

  // ws layout (floats):
  float* m1    = ws;                         // 2048
  float* v1    = ws + 2048;                  // 2048
  float* h     = ws + 8192;                  // 4,096,000 f32 region
  float* out1  = h    + (long)TOT;           // 4,096,000 f32
  float* outn  = out1 + (long)TOT;           // 4,096,000 f32 region
  float* xz    = outn + (long)TOT;           // 16,384,000 f32
  float* xc    = xz   + (long)ROWS * E2c;    // 8,192,000 f32
  float* xdbl  = xc   + (long)ROWS * DIc;    // 288,768 f32
  float* dtb   = xdbl + (long)ROWS * EXc;    // 8,192,000 f32 (holds dtv after dt gemm)

  // region reuse (stream-order lifetimes verified):
  unsigned short* An      = (unsigned short*)outn;             // 2048x2048 bf16; live: ln_rows -> W_in gemm
  unsigned short* Bwin8   = (unsigned short*)xc;               // 8192x2048 bf16 = 33.55MB; live: cvt -> W_in gemm
  unsigned short* Bwx     = (unsigned short*)outn;             // [0, 512K fl); after An dead
  unsigned short* Bwdt    = (unsigned short*)(outn + 512000);  // [512K, 774,144 fl); rows 4000..4095 ZERO
  float*          xdbl_sl = outn + 800000;                     // [800K, 2.90M fl)
  unsigned short* xdbl_b  = (unsigned short*)(outn + 2900000); // [2.90M, 3.04M fl)
  unsigned short* W1b     = (unsigned short*)(outn + 3100000); // 128x128 bf16
  unsigned short* W3b     = (unsigned short*)(outn + 3200000); // 128x128 bf16 (live to end)
  unsigned short* hT      = (unsigned short*)h;                // (16,2048,128) bf16
  unsigned short* xcb     = (unsigned short*)h;                // 2048x4000 bf16; live: dwconv -> xdbl gemm
  unsigned short* Bwout   = (unsigned short*)h;                // 2048x4000 bf16; live: cvt -> W_out gemm
  unsigned short* yb      = (unsigned short*)out;              // live: scan -> W_out gemm
  float*          wout_sl = xz;                                // 4 x 4,096,000 f32 slices
  const unsigned short* zsrc = (const unsigned short*)(outn + 768000); // Bwdt zero pad rows

  dim3 b256(256);
  int gElem = (TOT + 255) / 256;

  // ---- conv weights bf16 (both blocks, one launch) ----
  cvt_convw2<<<dim3(128), b256, 0, stream>>>(conv1_w, conv3_w, W1b, W3b);

  // ---- block 1: inorm+bn+relu fused with transpose -> hT bf16 ----
  inorm_stats<<<dim3(Bc * Cc), b256, 0, stream>>>(x, m1, v1);
  compute_h_t<<<dim3(32, Bc), b256, 0, stream>>>(x, m1, v1, bn1_g, bn1_b, hT);
  { // out1[b][o][n] = sum_c W1[o][c] * hT[b][n][c] + conv1_b[o]  (K=128 single-stage)
    dim3 g(16, 1, Bc);
    gemm_k128<<<g, b256, 0, stream>>>(W1b, hT, out1, Nc, Nc,
                                      0L, 2048L * 128, (long)Cc * Nc,
                                      3, conv1_b, nullptr);
  }

  // ---- layernorm -> bf16 An (K-padded to 2048) ----
  ln_rows<<<dim3(ROWS), b256, 0, stream>>>(out1, ln_w, ln_b, An);

  // ---- W_in -> bf16 padded (8192 x 2048) in dead xc region ----
  {
    long tot = (long)NP8 * KP1;
    cvt_pad_bf16<<<dim3((unsigned)((tot + 255) / 256)), b256, 0, stream>>>(
        W_in, Bwin8, NP8, KP1, E2c, Nc);
  }

  // ---- xz = outn @ W_in^T  (8-phase 256x256 MFMA, silu on z half) ----
  gemm_win_8ph<<<dim3(NP8 / 256, ROWS / 256), dim3(512), 0, stream>>>(An, Bwin8, xz);

  // ---- W_x + W_dt bf16 conversions (An now dead), one launch ----
  cvt_wx_wdt<<<dim3((256 * 4000 + 4096 * 128 + 255) / 256), b256, 0, stream>>>(
      W_x, W_dt, Bwx, Bwdt);

  // ---- depthwise conv + silu -> xc f32 + xcb bf16 (hT dead; Bwin8 dead) ----
  {
    int tot = ROWS * DIc;
    dwconv_silu<<<dim3((tot + 255) / 256), b256, 0, stream>>>(
        xz, (const float4*)convm_w, convm_b, xc, xcb, tot);
  }

  // ---- xdbl = xc @ W_x^T  (MFMA bf16, KS=4 slices) ----
  {
    dim3 g(2, ROWS / 128, 4);
    gemm_mfma_bt<<<g, b256, 0, stream>>>(xcb, Bwx, xdbl_sl, 256, DIc,
                                         DIc, DIc, 256, 0L, 0L, 0L,
                                         4, 1024, 2048L * 256, 0, nullptr, nullptr);
    int tot = 2048 * 144;
    reduce_xdbl<<<dim3((tot + 255) / 256), b256, 0, stream>>>(xdbl_sl, xdbl, xdbl_b);
  }

  // ---- dtv = softplus(xdbl_b @ W_dt^T + b_dt)  (K=128 single-stage, epi=1) ----
  {
    dim3 g(4096 / 128, ROWS / 128, 1);
    gemm_k128<<<g, b256, 0, stream>>>(xdbl_b, Bwdt, dtb, DIc, DIc,
                                      0L, 0L, 0L, 1, b_dt, nullptr);
  }

  // ---- W_out -> bf16 (2048 x 4000) in h region (xcb dead) ----
  {
    long tot = (long)2048 * DIc;
    cvt_pad_bf16<<<dim3((unsigned)((tot + 255) / 256)), b256, 0, stream>>>(
        W_out, Bwout, 2048, DIc, Nc, DIc);
  }

  // ---- selective scan (pipelined, 1 thread/(b,d)) -> yb bf16 ----
  scan_kernel<<<dim3((DIc + 255) / 256, Bc), b256, 0, stream>>>(
      dtb, xdbl, xc, xz, A_log, D_p, yb);

  // ---- y @ W_out^T  (8-phase 256x256 MFMA, split-K=4, zero-redirect
  //      K-tail; slices in dead xz region) ----
  gemm_wout_8ph<<<dim3(8, 8, 4), dim3(512), 0, stream>>>(yb, Bwout, wout_sl, zsrc);
  reduce_slices<<<dim3(gElem), b256, 0, stream>>>(
      wout_sl, out1, (long)TOT, 4, TOT, 1);

  // ---- block 3 on out1 -> d_out = conv3(h3) + conv3_b + x ----
  inorm_stats<<<dim3(Bc * Cc), b256, 0, stream>>>(out1, m1, v1);
  compute_h_t<<<dim3(32, Bc), b256, 0, stream>>>(out1, m1, v1, bn3_g, bn3_b, hT);
  { // K=128 single-stage, epi=3 with residual add
    dim3 g(16, 1, Bc);
    gemm_k128<<<g, b256, 0, stream>>>(W3b, hT, out, Nc, Nc,
                                      0L, 2048L * 128, (long)Cc * Nc,
                                      3, conv3_b, x);
  }
}

// Round 6
// 533.403 us; speedup vs baseline: 1.0859x; 1.0859x over previous
//
#include <hip/hip_runtime.h>
#include <cmath>
#include <cstdint>

#define Bc   16
#define Cc   128
#define Nc   2000
#define Lc   128      // sequence length for mamba = C
#define DIc  4000
#define Sc   8
#define RKc  125      // DT_RANK
#define E2c  8000     // 2*DI
#define EXc  141      // DT_RANK + 2*S
#define TOTc (Bc * Cc * Nc)   // 4,096,000

// padded dims for the 8-phase W_in GEMM (xz = outn @ W_in^T)
#define KP1  2048     // 2000 -> mult of 128 (2 K-tiles of 64 per iter)
#define NP8  8192     // 8000 -> mult of 256
#define KT8  32       // K tiles of 64

__device__ __forceinline__ unsigned short f2bf(float f) {
  union { float f; unsigned int u; } v; v.f = f;
  unsigned int r = v.u + 0x7FFFu + ((v.u >> 16) & 1u);
  return (unsigned short)(r >> 16);
}

// ------------------------------------------------------------------
// K1: per-(b,c) instance-norm stats over N (mean, biased var)
// ------------------------------------------------------------------
__global__ void inorm_stats(const float* __restrict__ in,
                            float* __restrict__ mout,
                            float* __restrict__ vout) {
  int bc = blockIdx.x;
  const float* p = in + (long)bc * Nc;
  float s = 0.f, sq = 0.f;
  for (int i = threadIdx.x; i < Nc; i += blockDim.x) {
    float x = p[i]; s += x; sq += x * x;
  }
  #pragma unroll
  for (int o = 32; o > 0; o >>= 1) {
    s  += __shfl_down(s, o, 64);
    sq += __shfl_down(sq, o, 64);
  }
  __shared__ float ss[4], sqq[4];
  int w = threadIdx.x >> 6, lane = threadIdx.x & 63;
  if (lane == 0) { ss[w] = s; sqq[w] = sq; }
  __syncthreads();
  if (threadIdx.x == 0) {
    s  = ss[0] + ss[1] + ss[2] + ss[3];
    sq = sqq[0] + sqq[1] + sqq[2] + sqq[3];
    float mean = s / Nc;
    float var  = sq / Nc - mean * mean;
    mout[bc] = mean; vout[bc] = var;
  }
}

// ------------------------------------------------------------------
// Fused: reduce 4 W_out slices into out1 AND compute block-3 inorm
// stats on the reduced values. One block per (b,c) row. Removes a
// full 16.4 MB re-read pass + a launch vs reduce_slices+inorm_stats.
// ------------------------------------------------------------------
__global__ void reduce_stats(const float* __restrict__ sl,
                             float* __restrict__ dst,
                             float* __restrict__ mout,
                             float* __restrict__ vout) {
  int bc = blockIdx.x;
  long base = (long)bc * Nc;
  float s = 0.f, sq = 0.f;
  for (int n = threadIdx.x; n < Nc; n += blockDim.x) {
    long i = base + n;
    float v = dst[i] + sl[i] + sl[i + (long)TOTc] + sl[i + 2L * TOTc] + sl[i + 3L * TOTc];
    dst[i] = v;
    s += v; sq += v * v;
  }
  #pragma unroll
  for (int o = 32; o > 0; o >>= 1) {
    s  += __shfl_down(s, o, 64);
    sq += __shfl_down(sq, o, 64);
  }
  __shared__ float ss[4], sqq[4];
  int w = threadIdx.x >> 6, lane = threadIdx.x & 63;
  if (lane == 0) { ss[w] = s; sqq[w] = sq; }
  __syncthreads();
  if (threadIdx.x == 0) {
    s  = ss[0] + ss[1] + ss[2] + ss[3];
    sq = sqq[0] + sqq[1] + sqq[2] + sqq[3];
    float mean = s / Nc;
    float var  = sq / Nc - mean * mean;
    mout[bc] = mean; vout[bc] = var;
  }
}

// ------------------------------------------------------------------
// K3: h^T = relu( inorm(x) * bnscale[c] * g[c] + b[c] ) transposed to
// (b, n, c) bf16 via LDS tile — the MFMA B^T operand layout.
// bn_scale folded in. grid (32, Bc), block 256.
// ------------------------------------------------------------------
__global__ void compute_h_t(const float* __restrict__ in,
                            const float* __restrict__ m,
                            const float* __restrict__ v,
                            const float* __restrict__ g,
                            const float* __restrict__ bb,
                            unsigned short* __restrict__ hT) {
  int b  = blockIdx.y;
  int n0 = blockIdx.x * 64;
  __shared__ unsigned short tile[64][132];
  __shared__ float bnsc_s[128];
  int t  = threadIdx.x;
  if (t < 128) {
    float s = 0.f;
    #pragma unroll
    for (int bb2 = 0; bb2 < Bc; bb2++) {
      float vv = v[bb2 * Cc + t];
      s += vv / (vv + 1e-3f);
    }
    bnsc_s[t] = rsqrtf(s / Bc + 1e-5f);
  }
  __syncthreads();
  int nl = t & 63, cb = t >> 6;
  int n  = n0 + nl;
  #pragma unroll 4
  for (int p = 0; p < 32; p++) {
    int c = p * 4 + cb;
    float val = 0.f;
    if (n < Nc) {
      int bc = b * Cc + c;
      float xn = (in[(long)bc * Nc + n] - m[bc]) * rsqrtf(v[bc] + 1e-3f);
      val = fmaxf(xn * bnsc_s[c] * g[c] + bb[c], 0.f);
    }
    tile[nl][c] = f2bf(val);
  }
  __syncthreads();
  int r = t >> 2, c0 = (t & 3) * 32;
  int nr = n0 + r;
  if (nr < Nc) {
    unsigned int* dst = (unsigned int*)(hT + ((long)b * 2048 + nr) * 128 + c0);
    const unsigned short* src = &tile[r][c0];
    #pragma unroll
    for (int j = 0; j < 16; j++)
      dst[j] = *(const unsigned int*)(src + 2 * j);
  }
}

// ------------------------------------------------------------------
// reduce 8 xdbl slices (2048 x 256 each) -> xdbl f32 (2048 x 141)
// and xdbl_b bf16 (2048 x 128: cols 0..124, 125..127 zero)
// ------------------------------------------------------------------
__global__ void reduce_xdbl(const float* __restrict__ sl,
                            float* __restrict__ xd,
                            unsigned short* __restrict__ xdb) {
  int i = blockIdx.x * 256 + threadIdx.x;
  if (i >= 2048 * 144) return;
  int row = i / 144, c = i - row * 144;
  float s = 0.f;
  if (c < EXc) {
    #pragma unroll
    for (int k = 0; k < 8; k++) s += sl[(long)k * (2048 * 256) + (long)row * 256 + c];
    xd[(long)row * EXc + c] = s;
  }
  if (c < 128) xdb[(long)row * 128 + c] = f2bf(c < RKc ? s : 0.f);
}

// ------------------------------------------------------------------
// Vectorized W_in cvt: f32 (8000 x 2000) -> bf16 (8192 x 2048), pad 0.
// 4 cols/thread: float4 load + uint2 (4xbf16) store. 2000 % 4 == 0.
// ------------------------------------------------------------------
__global__ void cvt_win_v4(const float* __restrict__ W, unsigned short* __restrict__ dst) {
  int i = blockIdx.x * 256 + threadIdx.x;          // 8192*512 total
  int r  = i >> 9;
  int c4 = (i & 511) << 2;
  uint2 o = make_uint2(0u, 0u);
  if (r < E2c && c4 < Nc) {
    float4 v = *(const float4*)&W[(long)r * Nc + c4];
    o.x = (unsigned)f2bf(v.x) | ((unsigned)f2bf(v.y) << 16);
    o.y = (unsigned)f2bf(v.z) | ((unsigned)f2bf(v.w) << 16);
  }
  *(uint2*)&dst[(long)r * KP1 + c4] = o;
}

// ------------------------------------------------------------------
// Vectorized W_out cvt: f32 (2000 x 4000) -> bf16 (2048 x 4000), pad 0.
// ------------------------------------------------------------------
__global__ void cvt_wout_v4(const float* __restrict__ W, unsigned short* __restrict__ dst) {
  int i = blockIdx.x * 256 + threadIdx.x;          // 2048*1000 total
  if (i >= 2048 * 1000) return;
  int r  = i / 1000;
  int c4 = (i - r * 1000) << 2;
  uint2 o = make_uint2(0u, 0u);
  if (r < Nc) {
    float4 v = *(const float4*)&W[(long)r * DIc + c4];
    o.x = (unsigned)f2bf(v.x) | ((unsigned)f2bf(v.y) << 16);
    o.y = (unsigned)f2bf(v.z) | ((unsigned)f2bf(v.w) << 16);
  }
  *(uint2*)&dst[(long)r * DIc + c4] = o;
}

// ------------------------------------------------------------------
// merged conv1_w + conv3_w bf16 conversion (both 128x128 pure cvt)
// ------------------------------------------------------------------
__global__ void cvt_convw2(const float* __restrict__ w1, const float* __restrict__ w3,
                           unsigned short* __restrict__ d1, unsigned short* __restrict__ d3) {
  int i = blockIdx.x * 256 + threadIdx.x;
  if (i < 16384) d1[i] = f2bf(w1[i]);
  else if (i < 32768) d3[i - 16384] = f2bf(w3[i - 16384]);
}

// ------------------------------------------------------------------
// merged W_x + W_dt bf16 conversions (padded)
// ------------------------------------------------------------------
__global__ void cvt_wx_wdt(const float* __restrict__ Wx, const float* __restrict__ Wdt,
                           unsigned short* __restrict__ bwx, unsigned short* __restrict__ bwdt) {
  int i = blockIdx.x * 256 + threadIdx.x;
  if (i < 256 * 4000) {
    int r = i / 4000, c = i - r * 4000;
    bwx[i] = f2bf(r < EXc ? Wx[(long)r * 4000 + c] : 0.f);
  } else {
    int j = i - 256 * 4000;
    if (j < 4096 * 128) {
      int r = j >> 7, c = j & 127;
      bwdt[j] = f2bf((r < DIc && c < RKc) ? Wdt[(long)r * RKc + c] : 0.f);
    }
  }
}

// ------------------------------------------------------------------
// K4: LayerNorm rows -> writes bf16, K-padded to KP1 with zeros
// ------------------------------------------------------------------
__global__ void ln_rows(const float* __restrict__ in,
                        const float* __restrict__ lw,
                        const float* __restrict__ lb,
                        unsigned short* __restrict__ An) {
  int row = blockIdx.x;
  const float* p = in + (long)row * Nc;
  float s = 0.f, sq = 0.f;
  for (int i = threadIdx.x; i < Nc; i += blockDim.x) {
    float x = p[i]; s += x; sq += x * x;
  }
  #pragma unroll
  for (int o = 32; o > 0; o >>= 1) {
    s  += __shfl_down(s, o, 64);
    sq += __shfl_down(sq, o, 64);
  }
  __shared__ float ss[4], sqq[4];
  __shared__ float smean, srstd;
  int w = threadIdx.x >> 6, lane = threadIdx.x & 63;
  if (lane == 0) { ss[w] = s; sqq[w] = sq; }
  __syncthreads();
  if (threadIdx.x == 0) {
    s  = ss[0] + ss[1] + ss[2] + ss[3];
    sq = sqq[0] + sqq[1] + sqq[2] + sqq[3];
    float mean = s / Nc;
    float var  = sq / Nc - mean * mean;
    smean = mean; srstd = rsqrtf(var + 1e-5f);
  }
  __syncthreads();
  float mu = smean, rs = srstd;
  for (int i = threadIdx.x; i < KP1; i += blockDim.x) {
    float v = 0.f;
    if (i < Nc) v = (p[i] - mu) * rs * lw[i] + lb[i];
    An[(long)row * KP1 + i] = f2bf(v);
  }
}

// ------------------------------------------------------------------
// bf16 MFMA GEMM, B^T layout: C[i][j] = sum_k A[i][k] * B[j][k]
// 128x128 tile, 4 waves (2x2). Deep-K loop (used for the xdbl GEMM).
// epi: 0 none; 1 softplus(v + ebias[gj]) via fast __logf/__expf;
//      2 silu(v) for j>=DIc; 3 v + ebias[gi] (+ addp[idx]) — conv epi.
// ------------------------------------------------------------------
typedef short v8s __attribute__((ext_vector_type(8)));
typedef float v4f __attribute__((ext_vector_type(4)));

typedef const __attribute__((address_space(1))) unsigned int* as1_cu32p;
typedef __attribute__((address_space(3))) unsigned int* as3_u32p;

__device__ __forceinline__ void gload_lds16(const unsigned short* g, unsigned short* l) {
  __builtin_amdgcn_global_load_lds((as1_cu32p)(uintptr_t)g,
                                   (as3_u32p)(uintptr_t)l, 16, 0, 0);
}

__device__ __forceinline__ float gemm_epilogue_val(float v, int epi, int gi, int gj,
                                                   const float* __restrict__ ebias,
                                                   const float* __restrict__ X, long idx) {
  if (epi == 1) {
    float tr = v + ebias[gj];
    float e = __expf(-fabsf(tr));
    v = fmaxf(tr, 0.f) + __logf(1.f + e);      // softplus, fast transcendentals
  } else if (epi == 2) {
    if (gj >= DIc) v = v / (1.f + __expf(-v)); // silu on z half
  } else if (epi == 3) {
    v += ebias[gi];
    if (X) v += X[idx];
  }
  return v;
}

__global__ __launch_bounds__(256, 4)
void gemm_mfma_bt(const unsigned short* __restrict__ A,
                  const unsigned short* __restrict__ B,
                  float* C, int NN, int K, int lda, int ldb, int ldc,
                  long sA, long sB, long sC,
                  int KS, int Klen, long sliceStride,
                  int epi, const float* __restrict__ ebias,
                  const float* __restrict__ addp) {
  __shared__ unsigned short As[128 * 32];
  __shared__ unsigned short Bs[128 * 32];

  int z = blockIdx.z;
  int batch = z / KS, ks = z - batch * KS;
  const unsigned short* Ab = A + (long)batch * sA;
  const unsigned short* Bb = B + (long)batch * sB;
  float* Cs = C + (long)batch * sC + (long)ks * sliceStride;
  const float* X = addp ? addp + (long)batch * sC : nullptr;

  int k0 = ks * Klen;
  int kend = min(K, k0 + Klen);

  int i0 = blockIdx.y * 128;
  int j0 = blockIdx.x * 128;

  int t = threadIdx.x;
  int wave = t >> 6, lane = t & 63;
  int wm = wave >> 1, wn = wave & 1;

  int srow = lane >> 2;     // 0..15
  int scol = lane & 3;      // k-chunk (8 bf16 = 16B)
  const unsigned short* gA0 = Ab + (long)(i0 + wave * 32 + srow) * lda + scol * 8;
  const unsigned short* gA1 = gA0 + (long)16 * lda;
  const unsigned short* gB0 = Bb + (long)(j0 + wave * 32 + srow) * ldb + scol * 8;
  const unsigned short* gB1 = gB0 + (long)16 * ldb;
  unsigned short* lA0 = As + (wave * 32) * 32;
  unsigned short* lA1 = As + (wave * 32 + 16) * 32;
  unsigned short* lB0 = Bs + (wave * 32) * 32;
  unsigned short* lB1 = Bs + (wave * 32 + 16) * 32;

  int fr = lane & 15;       // input-frag row index
  int kq = lane >> 4;       // k-quad (8 elements each)

  v4f acc[4][4] = {};

  for (int kt = k0; kt < kend; kt += 32) {
    gload_lds16(gA0 + kt, lA0);
    gload_lds16(gA1 + kt, lA1);
    gload_lds16(gB0 + kt, lB0);
    gload_lds16(gB1 + kt, lB1);
    __syncthreads();

    v8s af[4], bfr[4];
    #pragma unroll
    for (int mt = 0; mt < 4; mt++)
      af[mt] = *(const v8s*)&As[(wm * 64 + mt * 16 + fr) * 32 + kq * 8];
    #pragma unroll
    for (int nt = 0; nt < 4; nt++)
      bfr[nt] = *(const v8s*)&Bs[(wn * 64 + nt * 16 + fr) * 32 + kq * 8];

    #pragma unroll
    for (int mt = 0; mt < 4; mt++)
      #pragma unroll
      for (int nt = 0; nt < 4; nt++)
        acc[mt][nt] = __builtin_amdgcn_mfma_f32_16x16x32_bf16(
            af[mt], bfr[nt], acc[mt][nt], 0, 0, 0);
    __syncthreads();
  }

  // C/D layout: row=(lane>>4)*4+reg (A's m), col=lane&15 (B's n)
  int orow = (lane >> 4) * 4;
  int ocol = lane & 15;
  #pragma unroll
  for (int mt = 0; mt < 4; mt++) {
    #pragma unroll
    for (int nt = 0; nt < 4; nt++) {
      int gi = i0 + wm * 64 + mt * 16 + orow;
      int gj = j0 + wn * 64 + nt * 16 + ocol;
      if (gj >= NN) continue;
      #pragma unroll
      for (int r = 0; r < 4; r++) {
        long idx = (long)(gi + r) * ldc + gj;
        Cs[idx] = gemm_epilogue_val(acc[mt][nt][r], epi, gi + r, gj, ebias, X, idx);
      }
    }
  }
}

// ------------------------------------------------------------------
// Single-stage K=128 GEMM (conv1/conv3/dt). Entire K staged in one
// burst (16 global_load_lds/thread in flight), ONE barrier, 64 MFMAs.
// ------------------------------------------------------------------
__global__ __launch_bounds__(256, 2)
void gemm_k128(const unsigned short* __restrict__ A,
               const unsigned short* __restrict__ B,
               float* C, int NN, int ldc,
               long sA, long sB, long sC,
               int epi, const float* __restrict__ ebias,
               const float* __restrict__ addp) {
  __shared__ unsigned short As[4 * 128 * 32];   // 32 KiB
  __shared__ unsigned short Bs[4 * 128 * 32];   // 32 KiB

  int batch = blockIdx.z;
  const unsigned short* Ab = A + (long)batch * sA;
  const unsigned short* Bb = B + (long)batch * sB;
  float* Cs = C + (long)batch * sC;
  const float* X = addp ? addp + (long)batch * sC : nullptr;

  int i0 = blockIdx.y * 128;
  int j0 = blockIdx.x * 128;

  int t = threadIdx.x;
  int wave = t >> 6, lane = t & 63;
  int wm = wave >> 1, wn = wave & 1;
  int srow = lane >> 2, scol = lane & 3;

  const unsigned short* gA0 = Ab + (long)(i0 + wave * 32 + srow) * 128 + scol * 8;
  const unsigned short* gB0 = Bb + (long)(j0 + wave * 32 + srow) * 128 + scol * 8;

  #pragma unroll
  for (int kt = 0; kt < 4; kt++) {
    gload_lds16(gA0 + kt * 32,            As + kt * 4096 + (wave * 32) * 32);
    gload_lds16(gA0 + 16 * 128 + kt * 32, As + kt * 4096 + (wave * 32 + 16) * 32);
    gload_lds16(gB0 + kt * 32,            Bs + kt * 4096 + (wave * 32) * 32);
    gload_lds16(gB0 + 16 * 128 + kt * 32, Bs + kt * 4096 + (wave * 32 + 16) * 32);
  }
  __syncthreads();

  int fr = lane & 15, kq = lane >> 4;
  v4f acc[4][4] = {};
  #pragma unroll
  for (int kk = 0; kk < 4; kk++) {
    v8s af[4], bfr[4];
    #pragma unroll
    for (int mt = 0; mt < 4; mt++)
      af[mt] = *(const v8s*)&As[kk * 4096 + (wm * 64 + mt * 16 + fr) * 32 + kq * 8];
    #pragma unroll
    for (int nt = 0; nt < 4; nt++)
      bfr[nt] = *(const v8s*)&Bs[kk * 4096 + (wn * 64 + nt * 16 + fr) * 32 + kq * 8];
    #pragma unroll
    for (int mt = 0; mt < 4; mt++)
      #pragma unroll
      for (int nt = 0; nt < 4; nt++)
        acc[mt][nt] = __builtin_amdgcn_mfma_f32_16x16x32_bf16(
            af[mt], bfr[nt], acc[mt][nt], 0, 0, 0);
  }

  int orow = (lane >> 4) * 4;
  int ocol = lane & 15;
  #pragma unroll
  for (int mt = 0; mt < 4; mt++) {
    #pragma unroll
    for (int nt = 0; nt < 4; nt++) {
      int gi = i0 + wm * 64 + mt * 16 + orow;
      int gj = j0 + wn * 64 + nt * 16 + ocol;
      if (gj >= NN) continue;
      #pragma unroll
      for (int r = 0; r < 4; r++) {
        long idx = (long)(gi + r) * ldc + gj;
        Cs[idx] = gemm_epilogue_val(acc[mt][nt][r], epi, gi + r, gj, ebias, X, idx);
      }
    }
  }
}

// ==================================================================
// Shared macros for the 8-phase 256x256 kernels (file scope; undef'd
// after the last user). MM references local aF/bF/acc of each kernel.
// ==================================================================
#define MM(mh, nh) do {                                                       \
    _Pragma("unroll")                                                         \
    for (int mt_ = 0; mt_ < 4; mt_++) {                                       \
      _Pragma("unroll")                                                       \
      for (int nt_ = 0; nt_ < 2; nt_++) {                                     \
        acc[(mh) * 4 + mt_][(nh) * 2 + nt_] = __builtin_amdgcn_mfma_f32_16x16x32_bf16( \
            aF[mt_][0], bF[nh][nt_][0], acc[(mh) * 4 + mt_][(nh) * 2 + nt_], 0, 0, 0); \
        acc[(mh) * 4 + mt_][(nh) * 2 + nt_] = __builtin_amdgcn_mfma_f32_16x16x32_bf16( \
            aF[mt_][1], bF[nh][nt_][1], acc[(mh) * 4 + mt_][(nh) * 2 + nt_], 0, 0, 0); \
      } }                                                                     \
  } while (0)
#define FENCE()   __asm__ volatile("" ::: "memory")
#define BARRIER() do { FENCE(); __builtin_amdgcn_s_barrier(); FENCE(); } while (0)
#define WAIT_LGKM0() do { __asm__ volatile("s_waitcnt lgkmcnt(0)" ::: "memory"); \
                          __builtin_amdgcn_sched_barrier(0); } while (0)
#define WAIT_VM(n) __asm__ volatile("s_waitcnt vmcnt(" #n ")" ::: "memory")

// ------------------------------------------------------------------
// W_in GEMM, 8-phase 256x256 schedule (T2 swizzle + T3/T4 counted vmcnt
// + T5 setprio). C[i][j] = sum_k An[i][k] * Bwin[j][k], epi: silu on
// j >= DIc. M=2048, N=8192 (stores guarded at 8000), K=2048.
// ------------------------------------------------------------------
__global__ __launch_bounds__(512, 2)
void gemm_win_8ph(const unsigned short* __restrict__ A,   // 2048 x 2048 bf16
                  const unsigned short* __restrict__ B,   // 8192 x 2048 bf16
                  float* __restrict__ C) {                // 2048 x 8000 f32
  __shared__ unsigned short As8[2 * 2 * 128 * 64];        // 64 KiB
  __shared__ unsigned short Bs8[2 * 2 * 128 * 64];        // 64 KiB

  const int lda = KP1, ldb = KP1, ldc = E2c;

  int i0 = blockIdx.y * 256;
  int j0 = blockIdx.x * 256;

  int t = threadIdx.x;
  int w = t >> 6, l = t & 63;
  int wm = w >> 2;          // 0..1
  int wn = w & 3;           // 0..3
  int w8 = w << 3;

  // staging per-thread constants (pre-swizzled global column chunk)
  int rw     = w8 + (l >> 3);                  // 0..63
  int scol16 = (l & 7) ^ ((l >> 3) & 7);
  const unsigned short* pA = A + (long)(i0 + rw) * lda + scol16 * 8;
  int gjrow = ((rw >> 5) << 6) + (rw & 31);
  const unsigned short* pB = B + (long)(j0 + gjrow) * ldb + scol16 * 8;

  // compute-side per-lane constants
  int fr   = l & 15;
  int kq   = l >> 4;
  int inr0 = ((kq ^ (fr & 7)) << 4);           // swizzled byte-in-row, ks=0
  int inr1 = inr0 ^ 64;                        // ks=1

  const char* asb = (const char*)As8;
  const char* bsb = (const char*)Bs8;

  v4f acc[8][4] = {};
  v8s aF[4][2], bF[2][2][2];

#define ST_A(bufi, h, tile) do {                                              \
    int kt_ = ((tile) < KT8 ? (tile) : (KT8 - 1)) * 64;                       \
    gload_lds16(pA + (long)((h) * 64) * lda + kt_,                            \
                As8 + (size_t)((((bufi) * 2 + (h)) * 128 + w8) * 64));        \
    gload_lds16(pA + (long)(128 + (h) * 64) * lda + kt_,                      \
                As8 + (size_t)((((bufi) * 2 + (h)) * 128 + 64 + w8) * 64));   \
  } while (0)
#define ST_B(bufi, h, tile) do {                                              \
    int kt_ = ((tile) < KT8 ? (tile) : (KT8 - 1)) * 64;                       \
    gload_lds16(pB + (long)((h) * 32) * ldb + kt_,                            \
                Bs8 + (size_t)((((bufi) * 2 + (h)) * 128 + w8) * 64));        \
    gload_lds16(pB + (long)(128 + (h) * 32) * ldb + kt_,                      \
                Bs8 + (size_t)((((bufi) * 2 + (h)) * 128 + 64 + w8) * 64));   \
  } while (0)
#define LD_A(bufi, mh) do {                                                   \
    const char* ab_ = asb + (size_t)(((((bufi) * 2 + (mh)) * 128) + wm * 64 + fr) * 128); \
    aF[0][0] = *(const v8s*)(ab_ +    0 + inr0); aF[0][1] = *(const v8s*)(ab_ +    0 + inr1); \
    aF[1][0] = *(const v8s*)(ab_ + 2048 + inr0); aF[1][1] = *(const v8s*)(ab_ + 2048 + inr1); \
    aF[2][0] = *(const v8s*)(ab_ + 4096 + inr0); aF[2][1] = *(const v8s*)(ab_ + 4096 + inr1); \
    aF[3][0] = *(const v8s*)(ab_ + 6144 + inr0); aF[3][1] = *(const v8s*)(ab_ + 6144 + inr1); \
  } while (0)
#define LD_B(bufi, nh) do {                                                   \
    const char* bb_ = bsb + (size_t)(((((bufi) * 2 + (nh)) * 128) + wn * 32 + fr) * 128); \
    bF[nh][0][0] = *(const v8s*)(bb_ +    0 + inr0); bF[nh][0][1] = *(const v8s*)(bb_ +    0 + inr1); \
    bF[nh][1][0] = *(const v8s*)(bb_ + 2048 + inr0); bF[nh][1][1] = *(const v8s*)(bb_ + 2048 + inr1); \
  } while (0)

  // prologue: tile0 fully -> buf0; tile1 {Ah0,Bh1,Ah1} -> buf1 (6 in flight)
  ST_A(0, 0, 0); ST_B(0, 0, 0); ST_B(0, 1, 0); ST_A(0, 1, 0);
  ST_A(1, 0, 1); ST_B(1, 1, 1); ST_A(1, 1, 1);
  WAIT_VM(6);
  BARRIER();

  #pragma unroll 1
  for (int it = 0; it < KT8 / 2; ++it) {
    int u = 2 * it;
    // ---- p1: (mh0,nh0) from buf0 ----
    LD_A(0, 0); LD_B(0, 0); ST_B(1, 0, u + 1);
    BARRIER(); WAIT_LGKM0();
    __builtin_amdgcn_s_setprio(1); MM(0, 0); __builtin_amdgcn_s_setprio(0);
    BARRIER();
    // ---- p2: (mh0,nh1) ----
    LD_B(0, 1); ST_A(0, 0, u + 2);
    BARRIER(); WAIT_LGKM0();
    __builtin_amdgcn_s_setprio(1); MM(0, 1); __builtin_amdgcn_s_setprio(0);
    BARRIER();
    // ---- p3: (mh1,nh1) ----
    LD_A(0, 1); ST_B(0, 1, u + 2);
    BARRIER(); WAIT_LGKM0();
    __builtin_amdgcn_s_setprio(1); MM(1, 1); __builtin_amdgcn_s_setprio(0);
    BARRIER();
    // ---- p4: (mh1,nh0), vmcnt(6): tile u+1 fully landed ----
    ST_A(0, 1, u + 2);
    BARRIER();
    __builtin_amdgcn_s_setprio(1); MM(1, 0); __builtin_amdgcn_s_setprio(0);
    WAIT_VM(6);
    BARRIER();
    // ---- p5: (mh0,nh0) from buf1 ----
    LD_A(1, 0); LD_B(1, 0); ST_B(0, 0, u + 2);
    BARRIER(); WAIT_LGKM0();
    __builtin_amdgcn_s_setprio(1); MM(0, 0); __builtin_amdgcn_s_setprio(0);
    BARRIER();
    // ---- p6: (mh0,nh1) ----
    LD_B(1, 1); ST_A(1, 0, u + 3);
    BARRIER(); WAIT_LGKM0();
    __builtin_amdgcn_s_setprio(1); MM(0, 1); __builtin_amdgcn_s_setprio(0);
    BARRIER();
    // ---- p7: (mh1,nh1) ----
    LD_A(1, 1); ST_B(1, 1, u + 3);
    BARRIER(); WAIT_LGKM0();
    __builtin_amdgcn_s_setprio(1); MM(1, 1); __builtin_amdgcn_s_setprio(0);
    BARRIER();
    // ---- p8: (mh1,nh0), vmcnt(6): tile u+2 fully landed ----
    ST_A(1, 1, u + 3);
    BARRIER();
    __builtin_amdgcn_s_setprio(1); MM(1, 0); __builtin_amdgcn_s_setprio(0);
    WAIT_VM(6);
    BARRIER();
  }
  WAIT_VM(0);   // drain clamped tail prefetches before endpgm

  // epilogue: row=(lane>>4)*4+reg, col=lane&15
  int orow4 = (l >> 4) * 4;
  int ocol  = l & 15;
  #pragma unroll
  for (int m = 0; m < 8; m++) {
    int gi = i0 + wm * 128 + m * 16 + orow4;
    #pragma unroll
    for (int n = 0; n < 4; n++) {
      int gj = j0 + wn * 64 + n * 16 + ocol;
      if (gj >= E2c) continue;
      #pragma unroll
      for (int r = 0; r < 4; r++) {
        float v = acc[m][n][r];
        if (gj >= DIc) v = v / (1.f + __expf(-v));  // silu on z half
        C[(long)(gi + r) * ldc + gj] = v;
      }
    }
  }
#undef ST_A
#undef ST_B
#undef LD_A
#undef LD_B
}

// ------------------------------------------------------------------
// W_out GEMM, same 8-phase 256x256 schedule, split-K=4.
// K=4000 padded to 4096 logical; tail tiles redirect global_load_lds
// source to a guaranteed-zero region (zsrc = Bwdt pad rows).
// ------------------------------------------------------------------
__global__ __launch_bounds__(512, 2)
void gemm_wout_8ph(const unsigned short* __restrict__ A,   // yb 2048 x 4000 bf16
                   const unsigned short* __restrict__ B,   // Bwout 2048 x 4000 bf16
                   float* __restrict__ C,                  // slices: 4 x 2048 x 2000 f32
                   const unsigned short* __restrict__ zsrc) {
  __shared__ unsigned short As8[2 * 2 * 128 * 64];
  __shared__ unsigned short Bs8[2 * 2 * 128 * 64];

  const int lda = 4000, ldb = 4000;

  int i0 = blockIdx.y * 256;
  int j0 = blockIdx.x * 256;
  int ks = blockIdx.z;
  int k0t = ks * 16;                           // first global K-tile of slice

  int t = threadIdx.x;
  int w = t >> 6, l = t & 63;
  int wm = w >> 2;
  int wn = w & 3;
  int w8 = w << 3;

  int rw     = w8 + (l >> 3);
  int scol16 = (l & 7) ^ ((l >> 3) & 7);
  const unsigned short* pA = A + (long)(i0 + rw) * lda + scol16 * 8;
  int gjrow = ((rw >> 5) << 6) + (rw & 31);
  const unsigned short* pB = B + (long)(j0 + gjrow) * ldb + scol16 * 8;

  int fr   = l & 15;
  int kq   = l >> 4;
  int inr0 = ((kq ^ (fr & 7)) << 4);
  int inr1 = inr0 ^ 64;

  const char* asb = (const char*)As8;
  const char* bsb = (const char*)Bs8;

  v4f acc[8][4] = {};
  v8s aF[4][2], bF[2][2][2];

#define ST_A2(bufi, h, lt) do {                                               \
    int gk_ = k0t + (((lt) < 16) ? (lt) : 15);                                \
    bool pad_ = (gk_ >= 62) && (gk_ == 63 || scol16 >= 4);                    \
    const unsigned short* s0_ = pad_ ? zsrc : pA + (long)((h) * 64) * lda + gk_ * 64;   \
    const unsigned short* s1_ = pad_ ? zsrc : pA + (long)(128 + (h) * 64) * lda + gk_ * 64; \
    gload_lds16(s0_, As8 + (size_t)((((bufi) * 2 + (h)) * 128 + w8) * 64));   \
    gload_lds16(s1_, As8 + (size_t)((((bufi) * 2 + (h)) * 128 + 64 + w8) * 64)); \
  } while (0)
#define ST_B2(bufi, h, lt) do {                                               \
    int gk_ = k0t + (((lt) < 16) ? (lt) : 15);                                \
    bool pad_ = (gk_ >= 62) && (gk_ == 63 || scol16 >= 4);                    \
    const unsigned short* s0_ = pad_ ? zsrc : pB + (long)((h) * 32) * ldb + gk_ * 64;   \
    const unsigned short* s1_ = pad_ ? zsrc : pB + (long)(128 + (h) * 32) * ldb + gk_ * 64; \
    gload_lds16(s0_, Bs8 + (size_t)((((bufi) * 2 + (h)) * 128 + w8) * 64));   \
    gload_lds16(s1_, Bs8 + (size_t)((((bufi) * 2 + (h)) * 128 + 64 + w8) * 64)); \
  } while (0)
#define LD_A2(bufi, mh) do {                                                  \
    const char* ab_ = asb + (size_t)(((((bufi) * 2 + (mh)) * 128) + wm * 64 + fr) * 128); \
    aF[0][0] = *(const v8s*)(ab_ +    0 + inr0); aF[0][1] = *(const v8s*)(ab_ +    0 + inr1); \
    aF[1][0] = *(const v8s*)(ab_ + 2048 + inr0); aF[1][1] = *(const v8s*)(ab_ + 2048 + inr1); \
    aF[2][0] = *(const v8s*)(ab_ + 4096 + inr0); aF[2][1] = *(const v8s*)(ab_ + 4096 + inr1); \
    aF[3][0] = *(const v8s*)(ab_ + 6144 + inr0); aF[3][1] = *(const v8s*)(ab_ + 6144 + inr1); \
  } while (0)
#define LD_B2(bufi, nh) do {                                                  \
    const char* bb_ = bsb + (size_t)(((((bufi) * 2 + (nh)) * 128) + wn * 32 + fr) * 128); \
    bF[nh][0][0] = *(const v8s*)(bb_ +    0 + inr0); bF[nh][0][1] = *(const v8s*)(bb_ +    0 + inr1); \
    bF[nh][1][0] = *(const v8s*)(bb_ + 2048 + inr0); bF[nh][1][1] = *(const v8s*)(bb_ + 2048 + inr1); \
  } while (0)

  // prologue: slice tile0 -> buf0; tile1 {Ah0,Bh1,Ah1} -> buf1
  ST_A2(0, 0, 0); ST_B2(0, 0, 0); ST_B2(0, 1, 0); ST_A2(0, 1, 0);
  ST_A2(1, 0, 1); ST_B2(1, 1, 1); ST_A2(1, 1, 1);
  WAIT_VM(6);
  BARRIER();

  #pragma unroll 1
  for (int it = 0; it < 8; ++it) {
    int u = 2 * it;
    LD_A2(0, 0); LD_B2(0, 0); ST_B2(1, 0, u + 1);
    BARRIER(); WAIT_LGKM0();
    __builtin_amdgcn_s_setprio(1); MM(0, 0); __builtin_amdgcn_s_setprio(0);
    BARRIER();
    LD_B2(0, 1); ST_A2(0, 0, u + 2);
    BARRIER(); WAIT_LGKM0();
    __builtin_amdgcn_s_setprio(1); MM(0, 1); __builtin_amdgcn_s_setprio(0);
    BARRIER();
    LD_A2(0, 1); ST_B2(0, 1, u + 2);
    BARRIER(); WAIT_LGKM0();
    __builtin_amdgcn_s_setprio(1); MM(1, 1); __builtin_amdgcn_s_setprio(0);
    BARRIER();
    ST_A2(0, 1, u + 2);
    BARRIER();
    __builtin_amdgcn_s_setprio(1); MM(1, 0); __builtin_amdgcn_s_setprio(0);
    WAIT_VM(6);
    BARRIER();
    LD_A2(1, 0); LD_B2(1, 0); ST_B2(0, 0, u + 2);
    BARRIER(); WAIT_LGKM0();
    __builtin_amdgcn_s_setprio(1); MM(0, 0); __builtin_amdgcn_s_setprio(0);
    BARRIER();
    LD_B2(1, 1); ST_A2(1, 0, u + 3);
    BARRIER(); WAIT_LGKM0();
    __builtin_amdgcn_s_setprio(1); MM(0, 1); __builtin_amdgcn_s_setprio(0);
    BARRIER();
    LD_A2(1, 1); ST_B2(1, 1, u + 3);
    BARRIER(); WAIT_LGKM0();
    __builtin_amdgcn_s_setprio(1); MM(1, 1); __builtin_amdgcn_s_setprio(0);
    BARRIER();
    ST_A2(1, 1, u + 3);
    BARRIER();
    __builtin_amdgcn_s_setprio(1); MM(1, 0); __builtin_amdgcn_s_setprio(0);
    WAIT_VM(6);
    BARRIER();
  }
  WAIT_VM(0);

  float* Cs = C + (long)ks * ((long)2048 * Nc);
  int orow4 = (l >> 4) * 4;
  int ocol  = l & 15;
  #pragma unroll
  for (int m = 0; m < 8; m++) {
    int gi = i0 + wm * 128 + m * 16 + orow4;
    #pragma unroll
    for (int n = 0; n < 4; n++) {
      int gj = j0 + wn * 64 + n * 16 + ocol;
      if (gj >= Nc) continue;
      #pragma unroll
      for (int r = 0; r < 4; r++)
        Cs[(long)(gi + r) * Nc + gj] = acc[m][n][r];
    }
  }
#undef ST_A2
#undef ST_B2
#undef LD_A2
#undef LD_B2
}

#undef MM
#undef FENCE
#undef BARRIER
#undef WAIT_LGKM0
#undef WAIT_VM

// ------------------------------------------------------------------
// K6: depthwise causal conv (DCONV=4) + silu, 2 channels per thread.
// float2 loads/stores (d even -> aligned); writes f32 xc + bf16 xcb.
// ------------------------------------------------------------------
__global__ void dwconv_silu2(const float* __restrict__ xz,
                             const float4* __restrict__ cw,
                             const float* __restrict__ cb,
                             float* __restrict__ xc,
                             unsigned short* __restrict__ xcb, int totalPairs) {
  int i = blockIdx.x * 256 + threadIdx.x;
  if (i >= totalPairs) return;
  int p  = i % (DIc / 2);
  int bl = i / (DIc / 2);
  int d  = p * 2;
  int l  = bl % Lc;
  int b  = bl / Lc;
  float4 w0 = cw[d], w1 = cw[d + 1];
  float a0 = cb[d], a1 = cb[d + 1];
  long rowbase = (long)(b * Lc) * E2c + d;
  int l0 = l - 3;
  if (l0 >= 0)     { float2 v = *(const float2*)&xz[rowbase + (long)l0 * E2c];
                     a0 += v.x * w0.x; a1 += v.y * w1.x; }
  if (l0 + 1 >= 0) { float2 v = *(const float2*)&xz[rowbase + (long)(l0 + 1) * E2c];
                     a0 += v.x * w0.y; a1 += v.y * w1.y; }
  if (l0 + 2 >= 0) { float2 v = *(const float2*)&xz[rowbase + (long)(l0 + 2) * E2c];
                     a0 += v.x * w0.z; a1 += v.y * w1.z; }
  { float2 v = *(const float2*)&xz[rowbase + (long)l * E2c];
    a0 += v.x * w0.w; a1 += v.y * w1.w; }
  float s0 = a0 / (1.f + __expf(-a0));
  float s1 = a1 / (1.f + __expf(-a1));
  long o = (long)bl * DIc + d;
  *(float2*)&xc[o] = make_float2(s0, s1);
  *(unsigned int*)&xcb[o] = (unsigned)f2bf(s0) | ((unsigned)f2bf(s1) << 16);
}

// ------------------------------------------------------------------
// K9: selective scan, 1 thread per (b,d), software-pipelined.
// dtv pre-softplus'd (dt-GEMM epilogue); z pre-silu'd (W_in epilogue).
// ------------------------------------------------------------------
#define SCU 4
__global__ __launch_bounds__(256)
void scan_kernel(const float* __restrict__ dtv,
                 const float* __restrict__ xdbl,
                 const float* __restrict__ xc,
                 const float* __restrict__ xzf,
                 const float* __restrict__ A_log,
                 const float* __restrict__ D_p,
                 unsigned short* __restrict__ yb) {
  int d = blockIdx.x * 256 + threadIdx.x;
  int b = blockIdx.y;
  if (d >= DIc) return;
  float Av[Sc];
  #pragma unroll
  for (int s = 0; s < Sc; s++) Av[s] = -__expf(A_log[d * Sc + s]);
  float Dp = D_p[d];
  float h[Sc];
  #pragma unroll
  for (int s = 0; s < Sc; s++) h[s] = 0.f;

  long base  = (long)(b * Lc) * DIc + d;
  long zbase = (long)(b * Lc) * E2c + DIc + d;
  const float* xrow = xdbl + (long)(b * Lc) * EXc + RKc;

  float d0[SCU], u0[SCU], z0[SCU], B0[SCU][Sc], C0[SCU][Sc];
  float d1[SCU], u1[SCU], z1[SCU], B1[SCU][Sc], C1[SCU][Sc];

#define LOADG(g, dd, uu, zz, BB, CC)                                        \
  { int l0_ = (g) * SCU;                                                    \
    _Pragma("unroll")                                                       \
    for (int u = 0; u < SCU; u++) {                                         \
      long idx = base + (long)(l0_ + u) * DIc;                              \
      dd[u] = dtv[idx];                                                     \
      uu[u] = xc[idx];                                                      \
      zz[u] = xzf[zbase + (long)(l0_ + u) * E2c];                           \
      const float* xr = xrow + (long)(l0_ + u) * EXc;                       \
      _Pragma("unroll")                                                     \
      for (int s = 0; s < Sc; s++) { BB[u][s] = xr[s]; CC[u][s] = xr[Sc + s]; } \
    } }

#define COMPG(g, dd, uu, zz, BB, CC)                                        \
  { int l0_ = (g) * SCU;                                                    \
    _Pragma("unroll")                                                       \
    for (int u = 0; u < SCU; u++) {                                         \
      float dv = dd[u], uv = uu[u];                                         \
      float du = dv * uv;                                                   \
      float p = 0.f;                                                        \
      _Pragma("unroll")                                                     \
      for (int s = 0; s < Sc; s++) {                                        \
        float dA = __expf(dv * Av[s]);                                      \
        h[s] = dA * h[s] + du * BB[u][s];                                   \
        p += h[s] * CC[u][s];                                               \
      }                                                                     \
      yb[base + (long)(l0_ + u) * DIc] = f2bf((p + uv * Dp) * zz[u]);       \
    } }

  LOADG(0, d0, u0, z0, B0, C0);
  #pragma unroll 1
  for (int g = 0; g < Lc / SCU; g += 2) {
    LOADG(g + 1, d1, u1, z1, B1, C1);
    COMPG(g, d0, u0, z0, B0, C0);
    if (g + 2 < Lc / SCU) LOADG(g + 2, d0, u0, z0, B0, C0);
    COMPG(g + 1, d1, u1, z1, B1, C1);
  }
#undef LOADG
#undef COMPG
}

// ------------------------------------------------------------------
// launch
// ------------------------------------------------------------------
extern "C" void kernel_launch(void* const* d_in, const int* in_sizes, int n_in,
                              void* d_out, int out_size, void* d_ws, size_t ws_size,
                              hipStream_t stream) {
  const float* x       = (const float*)d_in[0];
  const float* bn1_g   = (const float*)d_in[1];
  const float* bn1_b   = (const float*)d_in[2];
  const float* conv1_w = (const float*)d_in[3];
  const float* conv1_b = (const float*)d_in[4];
  const float* ln_w    = (const float*)d_in[5];
  const float* ln_b    = (const float*)d_in[6];
  const float* W_in    = (const float*)d_in[7];
  const float* convm_w = (const float*)d_in[8];
  const float* convm_b = (const float*)d_in[9];
  const float* W_x     = (const float*)d_in[10];
  const float* W_dt    = (const float*)d_in[11];
  const float* b_dt    = (const float*)d_in[12];
  const float* A_log   = (const float*)d_in[13];
  const float* D_p     = (const float*)d_in[14];
  const float* W_out   = (const float*)d_in[15];
  const float* bn3_g   = (const float*)d_in[16];
  const float* bn3_b   = (const float*)d_in[17];
  const float* conv3_w = (const float*)d_in[18];
  const float* conv3_b = (const float*)d_in[19];
  float* out = (float*)d_out;
  float* ws  = (float*)d_ws;

  const int TOT  = TOTc;             // 4,096,000
  const int ROWS = Bc * Lc;          // 2048

  // ws layout (floats):
  float* m1    = ws;                         // 2048
  float* v1    = ws + 2048;                  // 2048
  float* h     = ws + 8192;                  // 4,096,000 f32 region
  float* out1  = h    + (long)TOT;           // 4,096,000 f32
  float* outn  = out1 + (long)TOT;           // 4,096,000 f32 region
  float* xz    = outn + (long)TOT;           // 16,384,000 f32
  float* xc    = xz   + (long)ROWS * E2c;    // 8,192,000 f32
  float* xdbl  = xc   + (long)ROWS * DIc;    // 288,768 f32
  float* dtb   = xdbl + (long)ROWS * EXc;    // 8,192,000 f32 (xdbl slices, then dtv)

  // region reuse (stream-order lifetimes verified):
  unsigned short* An      = (unsigned short*)outn;             // 2048x2048 bf16; live: ln_rows -> W_in gemm
  unsigned short* Bwin8   = (unsigned short*)xc;               // 8192x2048 bf16 = 33.55MB; live: cvt -> W_in gemm
  unsigned short* Bwx     = (unsigned short*)outn;             // [0, 512K fl); after An dead
  unsigned short* Bwdt    = (unsigned short*)(outn + 512000);  // [512K, 774,144 fl); rows 4000..4095 ZERO
  float*          xdbl_sl = dtb;                               // 8 x 2048x256 f32 = 4.19M fl in dead dtb region;
                                                               // consumed by reduce_xdbl BEFORE dt gemm writes dtb
  unsigned short* xdbl_b  = (unsigned short*)(outn + 2900000); // [2.90M, 3.04M fl)
  unsigned short* W1b     = (unsigned short*)(outn + 3100000); // 128x128 bf16
  unsigned short* W3b     = (unsigned short*)(outn + 3200000); // 128x128 bf16 (live to end)
  unsigned short* hT      = (unsigned short*)h;                // (16,2048,128) bf16
  unsigned short* xcb     = (unsigned short*)h;                // 2048x4000 bf16; live: dwconv -> xdbl gemm
  unsigned short* Bwout   = (unsigned short*)h;                // 2048x4000 bf16; live: cvt -> W_out gemm
  unsigned short* yb      = (unsigned short*)out;              // live: scan -> W_out gemm
  float*          wout_sl = xz;                                // 4 x 4,096,000 f32 slices
  const unsigned short* zsrc = (const unsigned short*)(outn + 768000); // Bwdt zero pad rows

  dim3 b256(256);

  // ---- conv weights bf16 (both blocks, one launch) ----
  cvt_convw2<<<dim3(128), b256, 0, stream>>>(conv1_w, conv3_w, W1b, W3b);

  // ---- block 1: inorm+bn+relu fused with transpose -> hT bf16 ----
  inorm_stats<<<dim3(Bc * Cc), b256, 0, stream>>>(x, m1, v1);
  compute_h_t<<<dim3(32, Bc), b256, 0, stream>>>(x, m1, v1, bn1_g, bn1_b, hT);
  { // out1[b][o][n] = sum_c W1[o][c] * hT[b][n][c] + conv1_b[o]  (K=128 single-stage)
    dim3 g(16, 1, Bc);
    gemm_k128<<<g, b256, 0, stream>>>(W1b, hT, out1, Nc, Nc,
                                      0L, 2048L * 128, (long)Cc * Nc,
                                      3, conv1_b, nullptr);
  }

  // ---- layernorm -> bf16 An (K-padded to 2048) ----
  ln_rows<<<dim3(ROWS), b256, 0, stream>>>(out1, ln_w, ln_b, An);

  // ---- W_in -> bf16 padded (8192 x 2048), vectorized ----
  cvt_win_v4<<<dim3(NP8 * 512 / 256), b256, 0, stream>>>(W_in, Bwin8);

  // ---- xz = outn @ W_in^T  (8-phase 256x256 MFMA, silu on z half) ----
  gemm_win_8ph<<<dim3(NP8 / 256, ROWS / 256), dim3(512), 0, stream>>>(An, Bwin8, xz);

  // ---- W_x + W_dt bf16 conversions (An now dead), one launch ----
  cvt_wx_wdt<<<dim3((256 * 4000 + 4096 * 128 + 255) / 256), b256, 0, stream>>>(
      W_x, W_dt, Bwx, Bwdt);

  // ---- depthwise conv + silu, 2-wide -> xc f32 + xcb bf16 ----
  {
    int totalPairs = ROWS * DIc / 2;
    dwconv_silu2<<<dim3((totalPairs + 255) / 256), b256, 0, stream>>>(
        xz, (const float4*)convm_w, convm_b, xc, xcb, totalPairs);
  }

  // ---- xdbl = xc @ W_x^T  (MFMA bf16, KS=8: full GPU, half the
  //      latency-serial depth; slices in dead dtb region) ----
  {
    dim3 g(2, ROWS / 128, 8);
    gemm_mfma_bt<<<g, b256, 0, stream>>>(xcb, Bwx, xdbl_sl, 256, DIc,
                                         DIc, DIc, 256, 0L, 0L, 0L,
                                         8, 512, 2048L * 256, 0, nullptr, nullptr);
    int tot = 2048 * 144;
    reduce_xdbl<<<dim3((tot + 255) / 256), b256, 0, stream>>>(xdbl_sl, xdbl, xdbl_b);
  }

  // ---- dtv = softplus(xdbl_b @ W_dt^T + b_dt)  (K=128 single-stage, epi=1) ----
  {
    dim3 g(4096 / 128, ROWS / 128, 1);
    gemm_k128<<<g, b256, 0, stream>>>(xdbl_b, Bwdt, dtb, DIc, DIc,
                                      0L, 0L, 0L, 1, b_dt, nullptr);
  }

  // ---- W_out -> bf16 (2048 x 4000), vectorized (xcb dead) ----
  cvt_wout_v4<<<dim3((2048 * 1000 + 255) / 256), b256, 0, stream>>>(W_out, Bwout);

  // ---- selective scan (pipelined, 1 thread/(b,d)) -> yb bf16 ----
  scan_kernel<<<dim3((DIc + 255) / 256, Bc), b256, 0, stream>>>(
      dtb, xdbl, xc, xz, A_log, D_p, yb);

  // ---- y @ W_out^T  (8-phase 256x256 MFMA, split-K=4, zero-redirect
  //      K-tail; slices in dead xz region) ----
  gemm_wout_8ph<<<dim3(8, 8, 4), dim3(512), 0, stream>>>(yb, Bwout, wout_sl, zsrc);

  // ---- fused: reduce 4 slices into out1 + block-3 inorm stats ----
  reduce_stats<<<dim3(Bc * Cc), b256, 0, stream>>>(wout_sl, out1, m1, v1);

  // ---- block 3 on out1 -> d_out = conv3(h3) + conv3_b + x ----
  compute_h_t<<<dim3(32, Bc), b256, 0, stream>>>(out1, m1, v1, bn3_g, bn3_b, hT);
  { // K=128 single-stage, epi=3 with residual add
    dim3 g(16, 1, Bc);
    gemm_k128<<<g, b256, 0, stream>>>(W3b, hT, out, Nc, Nc,
                                      0L, 2048L * 128, (long)Cc * Nc,
                                      3, conv3_b, x);
  }
}